// Round 3
// baseline (5334.423 us; speedup 1.0000x reference)
//
#include <hip/hip_runtime.h>

// Problem constants (B,T,D,H,FF,L,CS,LC) = (8,512,512,8,2048,6,16,4)
#define B_ 8
#define T_ 512
#define D_ 512
#define H_ 8
#define FF_ 2048
#define L_ 6
#define CS_ 16
#define LC_ 4
#define DK_ 64
#define MT_ (B_*T_)   // 4096 rows of activations

typedef unsigned short u16;  // raw bf16

__device__ __forceinline__ float bf2f(u16 u){
  union { unsigned int i; float f; } c; c.i = ((unsigned int)u) << 16; return c.f;
}
__device__ __forceinline__ u16 f2bf(float f){
  union { float f; unsigned int i; } c; c.f = f;
  unsigned int x = c.i;
  return (u16)((x + 0x7FFFu + ((x >> 16) & 1u)) >> 16);  // RNE
}
// load input element i: inputs may be bf16 (flag=0) or f32 (flag=1)
__device__ __forceinline__ float ldin(const void* p, size_t i, int isf){
  return isf ? ((const float*)p)[i] : bf2f(((const u16*)p)[i]);
}

// ---------------- dtype detect: sample Wq (sigma=0.02) ----------------------
// bf16 data: every u16 decodes to |v| <= ~0.1. f32 data: even u16s are mantissa
// halves -> random exponent -> |v|>0.5 or NaN ~half the time.
__global__ void detect_kernel(const u16* __restrict__ w, int* __restrict__ flag){
  int t = threadIdx.x;  // 64 threads
  float v = bf2f(w[2*t]);
  float av = fabsf(v);
  int hit = (av > 0.5f) || !(av == av);
  unsigned long long m = __ballot(hit);
  if (t == 0) flag[0] = (__popcll(m) >= 4) ? 1 : 0;
}

// ---------------- init: x = in(xs)*sqrt(D), pe32 = f32(pos_emb) --------------
__global__ void init_kernel(const void* __restrict__ xs, const void* __restrict__ pe,
                            float* __restrict__ x, float* __restrict__ pe32,
                            const int* __restrict__ flag)
{
  int isf = flag[0];
  int stride = gridDim.x * blockDim.x;
  int i0 = blockIdx.x * blockDim.x + threadIdx.x;
  const float s = 22.62741699796952f;  // sqrt(512)
  for (int i = i0; i < B_*T_*D_; i += stride) x[i] = ldin(xs, i, isf) * s;
  for (int i = i0; i < T_*D_;    i += stride) pe32[i] = ldin(pe, i, isf);
}

// ---------------- LayerNorm: one block (256 thr) per row of 512 --------------
// OUTMODE 0: always f32 (workspace). OUTMODE 1: final output -> dtype follows
// the input dtype flag (f32 inputs => f32 out, bf16 inputs => bf16 out).
template <int OUTMODE>
__global__ __launch_bounds__(256) void ln_kernel(const float* __restrict__ x,
    const void* __restrict__ g, const void* __restrict__ b, size_t goff,
    void* __restrict__ outp, const int* __restrict__ flag)
{
  int isf = flag[0];
  int row = blockIdx.x;
  const float* xr = x + (size_t)row * D_;
  int t = threadIdx.x;
  float v0 = xr[t], v1 = xr[t + 256];
  float s = v0 + v1, s2 = v0*v0 + v1*v1;
  #pragma unroll
  for (int off = 32; off > 0; off >>= 1){ s += __shfl_down(s, off); s2 += __shfl_down(s2, off); }
  __shared__ float ps[4], ps2[4], mb[2];
  int w = t >> 6;
  if ((t & 63) == 0){ ps[w] = s; ps2[w] = s2; }
  __syncthreads();
  if (t == 0){
    float S = ps[0]+ps[1]+ps[2]+ps[3];
    float S2 = ps2[0]+ps2[1]+ps2[2]+ps2[3];
    float m = S * (1.0f / D_);
    float var = S2 * (1.0f / D_) - m*m;   // population var, matches jnp.var
    mb[0] = m; mb[1] = rsqrtf(var + 1e-5f);
  }
  __syncthreads();
  float m = mb[0], rs = mb[1];
  float o0 = (v0 - m) * rs * ldin(g, goff + t, isf)     + ldin(b, goff + t, isf);
  float o1 = (v1 - m) * rs * ldin(g, goff + t+256, isf) + ldin(b, goff + t+256, isf);
  if (OUTMODE == 0 || isf){
    float* outr = (float*)outp + (size_t)row * D_;
    outr[t] = o0; outr[t+256] = o1;
  } else {
    u16* outr = (u16*)outp + (size_t)row * D_;
    outr[t] = f2bf(o0); outr[t+256] = f2bf(o1);
  }
}

// ---------------- Tiled GEMM: C = A(f32,MxK) @ W(in,KxN) [+bias][relu][+resid]
#define BM 64
#define BN 64
#define BK 16

__global__ __launch_bounds__(256) void gemm_kernel(
    const float* __restrict__ A, const void* __restrict__ W, size_t woff0,
    const void* __restrict__ bias, size_t boff0, const float* __restrict__ resid,
    float* __restrict__ C, int M, int N, int K, int relu,
    size_t wstride, size_t cstride, const int* __restrict__ flag)
{
  int isf = flag[0];
  size_t woff = woff0 + (size_t)blockIdx.z * wstride;
  C += (size_t)blockIdx.z * cstride;
  __shared__ float As[BK][BM+1];
  __shared__ float Bs[BK][BN+1];
  int tid = threadIdx.x;
  int m0 = blockIdx.y * BM, n0 = blockIdx.x * BN;
  int tx = tid & 15, ty = tid >> 4;
  int arow = tid >> 2, acol = (tid & 3) << 2;   // A: 64 rows x 16 k, float4 per thread
  int brow = tid >> 4, bcol = (tid & 15) << 2;  // W: 16 k x 64 n, 4 elems per thread
  float c[4][4] = {};
  for (int k0 = 0; k0 < K; k0 += BK){
    float4 a4 = *(const float4*)(A + (size_t)(m0 + arow) * K + k0 + acol);
    As[acol+0][arow] = a4.x;
    As[acol+1][arow] = a4.y;
    As[acol+2][arow] = a4.z;
    As[acol+3][arow] = a4.w;
    size_t widx = woff + (size_t)(k0 + brow) * N + n0 + bcol;
    if (isf){
      float4 w4 = *(const float4*)((const float*)W + widx);
      Bs[brow][bcol+0] = w4.x; Bs[brow][bcol+1] = w4.y;
      Bs[brow][bcol+2] = w4.z; Bs[brow][bcol+3] = w4.w;
    } else {
      ushort4 w4 = *(const ushort4*)((const u16*)W + widx);
      Bs[brow][bcol+0] = bf2f(w4.x); Bs[brow][bcol+1] = bf2f(w4.y);
      Bs[brow][bcol+2] = bf2f(w4.z); Bs[brow][bcol+3] = bf2f(w4.w);
    }
    __syncthreads();
    #pragma unroll
    for (int kk = 0; kk < BK; ++kk){
      float a[4], bb[4];
      #pragma unroll
      for (int i = 0; i < 4; ++i) a[i] = As[kk][ty*4 + i];
      #pragma unroll
      for (int j = 0; j < 4; ++j) bb[j] = Bs[kk][tx*4 + j];
      #pragma unroll
      for (int i = 0; i < 4; ++i)
        #pragma unroll
        for (int j = 0; j < 4; ++j)
          c[i][j] = fmaf(a[i], bb[j], c[i][j]);
    }
    __syncthreads();
  }
  #pragma unroll
  for (int i = 0; i < 4; ++i){
    int row = m0 + ty*4 + i;
    size_t base = (size_t)row * N + n0 + tx*4;
    #pragma unroll
    for (int j = 0; j < 4; ++j){
      float val = c[i][j];
      if (bias)  val += ldin(bias, boff0 + n0 + tx*4 + j, isf);
      if (relu)  val = fmaxf(val, 0.0f);
      if (resid) val += resid[base + j];
      C[base + j] = val;
    }
  }
}

// ---------------- Fused chunked attention -----------------------------------
// block = (chunk ci, head h, batch b); rows [ci*16, ci*16+16); cols [max(ci-4,0)*16,(ci+1)*16)
// mask is analytic: all cols in that range are allowed for all 16 rows of the chunk.
__global__ __launch_bounds__(256) void attn_kernel(
    const float* __restrict__ q, const float* __restrict__ k, const float* __restrict__ v,
    const float* __restrict__ p, const void* __restrict__ pbu, const void* __restrict__ pbv,
    size_t pboff, float* __restrict__ o, const int* __restrict__ flag)
{
  int isf = flag[0];
  int ci = blockIdx.x, h = blockIdx.y, b = blockIdx.z;
  int t0 = ci * CS_;
  int cb = ci - LC_; if (cb < 0) cb = 0;
  int c0 = cb * CS_;
  int ncol = (ci + 1) * CS_ - c0;   // 16..80, multiple of 16
  __shared__ float qu[CS_][DK_], qv[CS_][DK_];
  __shared__ float buf[5*CS_][DK_];     // reused: K tile, then P tile, then V tile
  __shared__ float sc[CS_][5*CS_];
  __shared__ float red[CS_][16];
  int tid = threadIdx.x;

  const float* qbase = q + ((size_t)b * T_ + t0) * D_ + h * DK_;
  for (int i = tid; i < CS_*DK_; i += 256){
    int r = i >> 6, d = i & 63;
    float qq = qbase[(size_t)r * D_ + d];
    qu[r][d] = qq + ldin(pbu, pboff + h*DK_ + d, isf);
    qv[r][d] = qq + ldin(pbv, pboff + h*DK_ + d, isf);
  }
  const float* kbase = k + ((size_t)b * T_ + c0) * D_ + h * DK_;
  for (int i = tid; i < ncol*DK_; i += 256){
    int r = i >> 6, d = i & 63;
    buf[r][d] = kbase[(size_t)r * D_ + d];
  }
  __syncthreads();
  const float scale = 0.125f;  // 1/sqrt(64)
  for (int i = tid; i < CS_*ncol; i += 256){
    int r = i / ncol, cc = i - r*ncol;
    float s = 0.f;
    #pragma unroll
    for (int d = 0; d < DK_; ++d) s += qu[r][d] * buf[cc][d];
    sc[r][cc] = s * scale;
  }
  __syncthreads();
  const float* pbase = p + (size_t)c0 * D_ + h * DK_;
  for (int i = tid; i < ncol*DK_; i += 256){
    int r = i >> 6, d = i & 63;
    buf[r][d] = pbase[(size_t)r * D_ + d];
  }
  __syncthreads();
  for (int i = tid; i < CS_*ncol; i += 256){
    int r = i / ncol, cc = i - r*ncol;
    float s = 0.f;
    #pragma unroll
    for (int d = 0; d < DK_; ++d) s += qv[r][d] * buf[cc][d];
    sc[r][cc] += s * scale;
  }
  __syncthreads();
  // prefetch V into buf (sc passes done reading K/P)
  const float* vbase = v + ((size_t)b * T_ + c0) * D_ + h * DK_;
  for (int i = tid; i < ncol*DK_; i += 256){
    int r = i >> 6, d = i & 63;
    buf[r][d] = vbase[(size_t)r * D_ + d];
  }
  // softmax over ncol per row; 16 threads per row
  int r = tid >> 4, j = tid & 15;
  float mx = -3.0e38f;
  for (int cc = j; cc < ncol; cc += 16) mx = fmaxf(mx, sc[r][cc]);
  red[r][j] = mx;
  __syncthreads();
  float m = red[r][0];
  #pragma unroll
  for (int t2 = 1; t2 < 16; ++t2) m = fmaxf(m, red[r][t2]);
  float sum = 0.f;
  for (int cc = j; cc < ncol; cc += 16){
    float e = __expf(sc[r][cc] - m);
    sc[r][cc] = e; sum += e;
  }
  __syncthreads();
  red[r][j] = sum;
  __syncthreads();
  float S = red[r][0];
  #pragma unroll
  for (int t2 = 1; t2 < 16; ++t2) S += red[r][t2];
  float inv = 1.0f / S;
  for (int cc = j; cc < ncol; cc += 16) sc[r][cc] *= inv;
  __syncthreads();
  // O = attn @ V
  float* obase = o + ((size_t)b * T_ + t0) * D_ + h * DK_;
  for (int i = tid; i < CS_*DK_; i += 256){
    int rr = i >> 6, d = i & 63;
    float acc = 0.f;
    for (int cc = 0; cc < ncol; ++cc) acc += sc[rr][cc] * buf[cc][d];
    obase[(size_t)rr * D_ + d] = acc;
  }
}

// ---------------- launcher ---------------------------------------------------
extern "C" void kernel_launch(void* const* d_in, const int* in_sizes, int n_in,
                              void* d_out, int out_size, void* d_ws, size_t ws_size,
                              hipStream_t stream)
{
  // Standard mapping: 24 inputs incl. bool mask at index 2 (mask is analytic,
  // ignored). Defensive: if the harness dropped the mask (n_in==23), shift.
  int s0 = (n_in >= 24) ? 0 : -1;   // shift applied to indices >= 3
  const void* xs   = d_in[0];
  const void* pe   = d_in[1];
  const void* Wq   = d_in[3  + s0];
  const void* bq   = d_in[4  + s0];
  const void* Wk   = d_in[5  + s0];
  const void* bk   = d_in[6  + s0];
  const void* Wv   = d_in[7  + s0];
  const void* bv   = d_in[8  + s0];
  const void* Wo   = d_in[9  + s0];
  const void* bo   = d_in[10 + s0];
  const void* Wp   = d_in[11 + s0];
  const void* pbu  = d_in[12 + s0];
  const void* pbv  = d_in[13 + s0];
  const void* ln1s = d_in[14 + s0];
  const void* ln1b = d_in[15 + s0];
  const void* ln2s = d_in[16 + s0];
  const void* ln2b = d_in[17 + s0];
  const void* W1   = d_in[18 + s0];
  const void* b1   = d_in[19 + s0];
  const void* W2   = d_in[20 + s0];
  const void* b2   = d_in[21 + s0];
  const void* lnfs = d_in[22 + s0];
  const void* lnfb = d_in[23 + s0];

  float* ws = (float*)d_ws;
  const size_t n = (size_t)MT_ * D_;       // 2,097,152
  int*   flag = (int*)ws;                  // ws[0..63]: dtype flag (+pad)
  float* x    = ws + 64;                   // n
  float* h    = x  + n;                    // n
  float* q    = h  + n;                    // n
  float* kb   = q  + n;                    // n
  float* vb   = kb + n;                    // n
  float* ob   = vb + n;                    // n
  float* ff   = q;                         // MT*FF = 4n, aliases q|kb|vb|ob (dead then)
  float* pe32 = ob + n;                    // T*D
  float* pbuf = pe32 + (size_t)T_ * D_;    // L*T*D
  // total: 64 + 6n + 7*T*D floats ~= 57.7 MB

  detect_kernel<<<dim3(1), dim3(64), 0, stream>>>((const u16*)Wq, flag);
  init_kernel<<<dim3(512), dim3(256), 0, stream>>>(xs, pe, x, pe32, flag);

  // all 6 layers' positional projection: P[l] = pe32 @ Wp[l]
  gemm_kernel<<<dim3(D_/BN, T_/BM, L_), dim3(256), 0, stream>>>(
      pe32, Wp, 0, nullptr, 0, nullptr, pbuf, T_, D_, D_, 0,
      (size_t)D_*D_, (size_t)T_*D_, flag);

  dim3 blk(256);
  dim3 gDD(D_/BN, MT_/BM, 1);   // 4096x512x512 GEMMs
  for (int l = 0; l < L_; ++l){
    const size_t oDD = (size_t)l * D_ * D_;
    const size_t oD  = (size_t)l * D_;
    const size_t oDF = (size_t)l * D_ * FF_;
    const size_t oFD = (size_t)l * FF_ * D_;
    const size_t oF  = (size_t)l * FF_;
    const size_t oHD = (size_t)l * H_ * DK_;

    ln_kernel<0><<<dim3(MT_), blk, 0, stream>>>(x, ln1s, ln1b, oD, h, flag);
    gemm_kernel<<<gDD, blk, 0, stream>>>(h, Wq, oDD, bq, oD, nullptr, q,  MT_, D_, D_, 0, 0, 0, flag);
    gemm_kernel<<<gDD, blk, 0, stream>>>(h, Wk, oDD, bk, oD, nullptr, kb, MT_, D_, D_, 0, 0, 0, flag);
    gemm_kernel<<<gDD, blk, 0, stream>>>(h, Wv, oDD, bv, oD, nullptr, vb, MT_, D_, D_, 0, 0, 0, flag);
    attn_kernel<<<dim3(T_/CS_, H_, B_), blk, 0, stream>>>(
        q, kb, vb, pbuf + (size_t)l*T_*D_, pbu, pbv, oHD, ob, flag);
    gemm_kernel<<<gDD, blk, 0, stream>>>(ob, Wo, oDD, bo, oD, x, x, MT_, D_, D_, 0, 0, 0, flag);
    ln_kernel<0><<<dim3(MT_), blk, 0, stream>>>(x, ln2s, ln2b, oD, h, flag);
    gemm_kernel<<<dim3(FF_/BN, MT_/BM, 1), blk, 0, stream>>>(h, W1, oDF, b1, oF, nullptr, ff, MT_, FF_, D_, 1, 0, 0, flag);
    gemm_kernel<<<dim3(D_/BN, MT_/BM, 1), blk, 0, stream>>>(ff, W2, oFD, b2, oD, x, x, MT_, D_, FF_, 0, 0, 0, flag);
  }
  ln_kernel<1><<<dim3(MT_), blk, 0, stream>>>(x, lnfs, lnfb, 0, d_out, flag);
}

// Round 4
// 1952.402 us; speedup vs baseline: 2.7322x; 2.7322x over previous
//
#include <hip/hip_runtime.h>

// Problem constants (B,T,D,H,FF,L,CS,LC) = (8,512,512,8,2048,6,16,4)
#define B_ 8
#define T_ 512
#define D_ 512
#define H_ 8
#define FF_ 2048
#define L_ 6
#define CS_ 16
#define LC_ 4
#define DK_ 64
#define MT_ (B_*T_)   // 4096 rows

typedef unsigned short u16;  // raw bf16
typedef __attribute__((ext_vector_type(8))) short bf8_t;   // 8 x bf16 (4 VGPR)
typedef __attribute__((ext_vector_type(4))) float f4_t;    // 4 x f32 acc

__device__ __forceinline__ float bf2f(u16 u){
  union { unsigned int i; float f; } c; c.i = ((unsigned int)u) << 16; return c.f;
}
__device__ __forceinline__ u16 f2bf(float f){
  union { float f; unsigned int i; } c; c.f = f;
  unsigned int x = c.i;
  return (u16)((x + 0x7FFFu + ((x >> 16) & 1u)) >> 16);  // RNE
}

// ---------------- init: x = xs*sqrt(D) (f32), pe_bf = bf16(pos_emb) ----------
__global__ void init_kernel(const float* __restrict__ xs, const float* __restrict__ pe,
                            float* __restrict__ x, u16* __restrict__ pe_bf)
{
  int stride = gridDim.x * blockDim.x;
  int i0 = blockIdx.x * blockDim.x + threadIdx.x;
  const float s = 22.62741699796952f;  // sqrt(512)
  for (int i = i0; i < B_*T_*D_; i += stride) x[i] = xs[i] * s;
  for (int i = i0; i < T_*D_;    i += stride) pe_bf[i] = f2bf(pe[i]);
}

// ---------------- generic transpose+convert: in f32 [K][N] -> out bf16 [N][K]
// grid: (N/32, K/32, nmats); block (32,8)
__global__ void transpose_kernel(const float* __restrict__ in, u16* __restrict__ out,
                                 int K, int N)
{
  __shared__ float tile[32][33];
  int l = blockIdx.z;
  const float* src = in + (size_t)l * K * N;
  u16* dst = out + (size_t)l * N * K;
  int n0 = blockIdx.x * 32, k0 = blockIdx.y * 32;
  int tx = threadIdx.x, ty = threadIdx.y;
  #pragma unroll
  for (int i = 0; i < 4; ++i)
    tile[ty + i*8][tx] = src[(size_t)(k0 + ty + i*8) * N + n0 + tx];
  __syncthreads();
  #pragma unroll
  for (int i = 0; i < 4; ++i)
    dst[(size_t)(n0 + ty + i*8) * K + k0 + tx] = f2bf(tile[tx][ty + i*8]);
}

// ---------------- QKV packed transpose: out[l][n][k], n<512:Wq, <1024:Wk, else Wv
// grid: (1536/32, 512/32, 6); block (32,8)
__global__ void transpose_qkv_kernel(const float* __restrict__ Wq, const float* __restrict__ Wk,
                                     const float* __restrict__ Wv, u16* __restrict__ out)
{
  __shared__ float tile[32][33];
  int l = blockIdx.z;
  int n0 = blockIdx.x * 32, k0 = blockIdx.y * 32;
  const float* W = (n0 < 512) ? Wq : (n0 < 1024 ? Wk : Wv);
  int nn0 = n0 & 511;
  const float* src = W + (size_t)l * D_ * D_;
  u16* dst = out + (size_t)l * 3 * D_ * D_;
  int tx = threadIdx.x, ty = threadIdx.y;
  #pragma unroll
  for (int i = 0; i < 4; ++i)
    tile[ty + i*8][tx] = src[(size_t)(k0 + ty + i*8) * D_ + nn0 + tx];
  __syncthreads();
  #pragma unroll
  for (int i = 0; i < 4; ++i)
    dst[(size_t)(n0 + ty + i*8) * D_ + k0 + tx] = f2bf(tile[tx][ty + i*8]);
}

// ---------------- bias pack: bqkv[l][1536] -----------------------------------
__global__ void pack_bias_kernel(const float* __restrict__ bq, const float* __restrict__ bk,
                                 const float* __restrict__ bv, float* __restrict__ out)
{
  int l = blockIdx.x, t = threadIdx.x;  // 512 threads
  out[l*1536 + t]        = bq[l*512 + t];
  out[l*1536 + 512  + t] = bk[l*512 + t];
  out[l*1536 + 1024 + t] = bv[l*512 + t];
}

// ---------------- LayerNorm ---------------------------------------------------
// OUTMODE 0: write bf16 (workspace activation). OUTMODE 1: write f32 (final out)
template <int OUTMODE>
__global__ __launch_bounds__(256) void ln_kernel(const float* __restrict__ x,
    const float* __restrict__ g, const float* __restrict__ b, void* __restrict__ outp)
{
  int row = blockIdx.x;
  const float* xr = x + (size_t)row * D_;
  int t = threadIdx.x;
  float v0 = xr[t], v1 = xr[t + 256];
  float s = v0 + v1, s2 = v0*v0 + v1*v1;
  #pragma unroll
  for (int off = 32; off > 0; off >>= 1){ s += __shfl_down(s, off); s2 += __shfl_down(s2, off); }
  __shared__ float ps[4], ps2[4], mb[2];
  int w = t >> 6;
  if ((t & 63) == 0){ ps[w] = s; ps2[w] = s2; }
  __syncthreads();
  if (t == 0){
    float S = ps[0]+ps[1]+ps[2]+ps[3];
    float S2 = ps2[0]+ps2[1]+ps2[2]+ps2[3];
    float m = S * (1.0f / D_);
    float var = S2 * (1.0f / D_) - m*m;   // population var, matches jnp.var
    mb[0] = m; mb[1] = rsqrtf(var + 1e-5f);
  }
  __syncthreads();
  float m = mb[0], rs = mb[1];
  float o0 = (v0 - m) * rs * g[t]     + b[t];
  float o1 = (v1 - m) * rs * g[t+256] + b[t+256];
  if (OUTMODE == 1){
    float* outr = (float*)outp + (size_t)row * D_;
    outr[t] = o0; outr[t+256] = o1;
  } else {
    u16* outr = (u16*)outp + (size_t)row * D_;
    outr[t] = f2bf(o0); outr[t+256] = f2bf(o1);
  }
}

// ---------------- MFMA GEMM ---------------------------------------------------
// C[M][N] = A[M][K](bf16) @ Bt[N][K](bf16)^T  [+bias][relu][+resid], out f32/bf16
// tile: 128(M) x TN(N), BK=32; 256 threads = 4 waves, wave grid 2x2,
// wave sub-tile 64 x TN/2. grid: (N/TN, M/128, Z).
template <int TN>
__global__ __launch_bounds__(256) void mgemm_kernel(
    const u16* __restrict__ A, const u16* __restrict__ Bt,
    const float* __restrict__ bias, const float* __restrict__ resid,
    void* __restrict__ C, int M, int N, int K,
    int relu, int bf16out, size_t wstride, size_t cstride)
{
  constexpr int NT = TN / 32;            // 16-col tiles per wave sub-tile
  Bt += (size_t)blockIdx.z * wstride;
  size_t coff = (size_t)blockIdx.z * cstride;

  __shared__ u16 As[128 * 32];           // [m][k], 8 KB
  __shared__ u16 Bs[TN * 32];            // [n][k]

  int tid  = threadIdx.x;
  int wave = tid >> 6, lane = tid & 63;
  int wm = wave >> 1, wn = wave & 1;
  int fm = lane & 15, fq = lane >> 4;    // frag row, quad

  int m0 = blockIdx.y * 128, n0 = blockIdx.x * TN;

  f4_t acc[4][NT];
  #pragma unroll
  for (int i = 0; i < 4; ++i)
    #pragma unroll
    for (int j = 0; j < NT; ++j) acc[i][j] = (f4_t)0.0f;

  int srow = lane >> 2;                  // staging row-in-chunk (16 rows/chunk)
  int selem = (lane & 3) * 8;            // staging k-element offset

  for (int k0 = 0; k0 < K; k0 += 32){
    // stage A: 8 chunks of 16 rows; wave w does chunks 2w, 2w+1
    #pragma unroll
    for (int j = 0; j < 2; ++j){
      int c = wave * 2 + j;
      const u16* gp = A + (size_t)(m0 + c*16 + srow) * K + k0 + selem;
      u16* lp = &As[c * 512];
      __builtin_amdgcn_global_load_lds((const __attribute__((address_space(1))) void*)gp,
                                       (__attribute__((address_space(3))) void*)lp, 16, 0, 0);
    }
    // stage B: TN/16 chunks
    #pragma unroll
    for (int j = 0; j < TN/64; ++j){
      int c = wave * (TN/64) + j;
      const u16* gp = Bt + (size_t)(n0 + c*16 + srow) * K + k0 + selem;
      u16* lp = &Bs[c * 512];
      __builtin_amdgcn_global_load_lds((const __attribute__((address_space(1))) void*)gp,
                                       (__attribute__((address_space(3))) void*)lp, 16, 0, 0);
    }
    __syncthreads();

    bf8_t af[4], bf[NT];
    #pragma unroll
    for (int mi = 0; mi < 4; ++mi)
      af[mi] = *(const bf8_t*)&As[(wm*64 + mi*16 + fm) * 32 + fq*8];
    #pragma unroll
    for (int nj = 0; nj < NT; ++nj)
      bf[nj] = *(const bf8_t*)&Bs[(wn*(TN/2) + nj*16 + fm) * 32 + fq*8];
    #pragma unroll
    for (int mi = 0; mi < 4; ++mi)
      #pragma unroll
      for (int nj = 0; nj < NT; ++nj)
        acc[mi][nj] = __builtin_amdgcn_mfma_f32_16x16x32_bf16(af[mi], bf[nj], acc[mi][nj], 0, 0, 0);
    __syncthreads();
  }

  // epilogue: C/D layout col = lane&15, row = (lane>>4)*4 + reg  [m89]
  int rbase = m0 + wm*64, cbase = n0 + wn*(TN/2);
  #pragma unroll
  for (int mi = 0; mi < 4; ++mi){
    #pragma unroll
    for (int nj = 0; nj < NT; ++nj){
      int col = cbase + nj*16 + fm;
      float bia = bias ? bias[col] : 0.0f;
      #pragma unroll
      for (int r = 0; r < 4; ++r){
        int row = rbase + mi*16 + fq*4 + r;
        size_t idx = coff + (size_t)row * N + col;
        float val = acc[mi][nj][r] + bia;
        if (relu)  val = fmaxf(val, 0.0f);
        if (resid) val += resid[idx];
        if (bf16out) ((u16*)C)[idx] = f2bf(val);
        else         ((float*)C)[idx] = val;
      }
    }
  }
}

// ---------------- Fused chunked attention ------------------------------------
// qkv bf16 [4096][1536] (q|k|v each 512 cols), p bf16 [512][512],
// pbu/pbv f32 [512] (layer-folded), out bf16 [4096][512].
__global__ __launch_bounds__(256) void attn_kernel(
    const u16* __restrict__ qkv, const u16* __restrict__ p,
    const float* __restrict__ pbu, const float* __restrict__ pbv,
    u16* __restrict__ o)
{
  int ci = blockIdx.x, h = blockIdx.y, b = blockIdx.z;
  int t0 = ci * CS_;
  int cb = ci - LC_; if (cb < 0) cb = 0;
  int c0 = cb * CS_;
  int ncol = (ci + 1) * CS_ - c0;   // 16..80
  __shared__ float qu[CS_][DK_], qv[CS_][DK_];
  __shared__ float buf[5*CS_][DK_];     // K tile -> P tile -> V tile
  __shared__ float sc[CS_][5*CS_];
  __shared__ float red[CS_][16];
  int tid = threadIdx.x;

  const u16* qbase = qkv + ((size_t)(b*T_ + t0)) * 1536 + h*DK_;
  for (int i = tid; i < CS_*DK_; i += 256){
    int r = i >> 6, d = i & 63;
    float qq = bf2f(qbase[(size_t)r * 1536 + d]);
    qu[r][d] = qq + pbu[h*DK_ + d];
    qv[r][d] = qq + pbv[h*DK_ + d];
  }
  const u16* kbase = qkv + ((size_t)(b*T_ + c0)) * 1536 + 512 + h*DK_;
  for (int i = tid; i < ncol*DK_; i += 256){
    int r = i >> 6, d = i & 63;
    buf[r][d] = bf2f(kbase[(size_t)r * 1536 + d]);
  }
  __syncthreads();
  const float scale = 0.125f;  // 1/sqrt(64)
  for (int i = tid; i < CS_*ncol; i += 256){
    int r = i / ncol, cc = i - r*ncol;
    float s = 0.f;
    #pragma unroll
    for (int d = 0; d < DK_; ++d) s += qu[r][d] * buf[cc][d];
    sc[r][cc] = s * scale;
  }
  __syncthreads();
  const u16* pbase = p + (size_t)c0 * D_ + h*DK_;
  for (int i = tid; i < ncol*DK_; i += 256){
    int r = i >> 6, d = i & 63;
    buf[r][d] = bf2f(pbase[(size_t)r * D_ + d]);
  }
  __syncthreads();
  for (int i = tid; i < CS_*ncol; i += 256){
    int r = i / ncol, cc = i - r*ncol;
    float s = 0.f;
    #pragma unroll
    for (int d = 0; d < DK_; ++d) s += qv[r][d] * buf[cc][d];
    sc[r][cc] += s * scale;
  }
  __syncthreads();
  const u16* vbase = qkv + ((size_t)(b*T_ + c0)) * 1536 + 1024 + h*DK_;
  for (int i = tid; i < ncol*DK_; i += 256){
    int r = i >> 6, d = i & 63;
    buf[r][d] = bf2f(vbase[(size_t)r * 1536 + d]);
  }
  // softmax (16 threads per row)
  int r = tid >> 4, j = tid & 15;
  float mx = -3.0e38f;
  for (int cc = j; cc < ncol; cc += 16) mx = fmaxf(mx, sc[r][cc]);
  red[r][j] = mx;
  __syncthreads();
  float m = red[r][0];
  #pragma unroll
  for (int t2 = 1; t2 < 16; ++t2) m = fmaxf(m, red[r][t2]);
  float sum = 0.f;
  for (int cc = j; cc < ncol; cc += 16){
    float e = __expf(sc[r][cc] - m);
    sc[r][cc] = e; sum += e;
  }
  __syncthreads();
  red[r][j] = sum;
  __syncthreads();
  float S = red[r][0];
  #pragma unroll
  for (int t2 = 1; t2 < 16; ++t2) S += red[r][t2];
  float inv = 1.0f / S;
  for (int cc = j; cc < ncol; cc += 16) sc[r][cc] *= inv;
  __syncthreads();
  u16* obase = o + ((size_t)(b*T_ + t0)) * D_ + h*DK_;
  for (int i = tid; i < CS_*DK_; i += 256){
    int rr = i >> 6, d = i & 63;
    float acc = 0.f;
    for (int cc = 0; cc < ncol; ++cc) acc += sc[rr][cc] * buf[cc][d];
    obase[(size_t)rr * D_ + d] = f2bf(acc);
  }
}

// ---------------- launcher ---------------------------------------------------
extern "C" void kernel_launch(void* const* d_in, const int* in_sizes, int n_in,
                              void* d_out, int out_size, void* d_ws, size_t ws_size,
                              hipStream_t stream)
{
  int s0 = (n_in >= 24) ? 0 : -1;
  const float* xs   = (const float*)d_in[0];
  const float* pe   = (const float*)d_in[1];
  const float* Wq   = (const float*)d_in[3  + s0];
  const float* bq   = (const float*)d_in[4  + s0];
  const float* Wk   = (const float*)d_in[5  + s0];
  const float* bk   = (const float*)d_in[6  + s0];
  const float* Wv   = (const float*)d_in[7  + s0];
  const float* bv   = (const float*)d_in[8  + s0];
  const float* Wo   = (const float*)d_in[9  + s0];
  const float* bo   = (const float*)d_in[10 + s0];
  const float* Wp   = (const float*)d_in[11 + s0];
  const float* pbu  = (const float*)d_in[12 + s0];
  const float* pbv  = (const float*)d_in[13 + s0];
  const float* ln1s = (const float*)d_in[14 + s0];
  const float* ln1b = (const float*)d_in[15 + s0];
  const float* ln2s = (const float*)d_in[16 + s0];
  const float* ln2b = (const float*)d_in[17 + s0];
  const float* W1   = (const float*)d_in[18 + s0];
  const float* b1   = (const float*)d_in[19 + s0];
  const float* W2   = (const float*)d_in[20 + s0];
  const float* b2   = (const float*)d_in[21 + s0];
  const float* lnfs = (const float*)d_in[22 + s0];
  const float* lnfb = (const float*)d_in[23 + s0];

  float* ws = (float*)d_ws;
  size_t cur = 0;
  float* x      = ws + cur;            cur += (size_t)MT_*D_;        // 2,097,152
  u16*   region = (u16*)(ws + cur);    cur += (size_t)MT_*FF_/2;     // 8M u16: qkv(6M)|ff(8M) alias
  u16*   qkv_bf = region;
  u16*   ff_bf  = region;
  u16*   h_bf   = (u16*)(ws + cur);    cur += (size_t)MT_*D_/2;
  u16*   ob_bf  = (u16*)(ws + cur);    cur += (size_t)MT_*D_/2;
  u16*   pe_bf  = (u16*)(ws + cur);    cur += (size_t)T_*D_/2;
  u16*   pbuf   = (u16*)(ws + cur);    cur += (size_t)L_*T_*D_/2;
  u16*   qkvt   = (u16*)(ws + cur);    cur += (size_t)L_*3*D_*D_/2;
  u16*   wot    = (u16*)(ws + cur);    cur += (size_t)L_*D_*D_/2;
  u16*   w1t    = (u16*)(ws + cur);    cur += (size_t)L_*D_*FF_/2;
  u16*   w2t    = (u16*)(ws + cur);    cur += (size_t)L_*FF_*D_/2;
  u16*   wpt    = (u16*)(ws + cur);    cur += (size_t)L_*D_*D_/2;
  float* bqkv   = ws + cur;            cur += (size_t)L_*3*D_;
  // total ~19.5M floats ~78 MB

  dim3 tb(32, 8);
  // weight conversion (every launch; ws is re-poisoned by harness)
  transpose_qkv_kernel<<<dim3(48, 16, L_), tb, 0, stream>>>(Wq, Wk, Wv, qkvt);
  transpose_kernel<<<dim3(16, 16, L_), tb, 0, stream>>>(Wo, wot, D_, D_);
  transpose_kernel<<<dim3(64, 16, L_), tb, 0, stream>>>(W1, w1t, D_, FF_);
  transpose_kernel<<<dim3(16, 64, L_), tb, 0, stream>>>(W2, w2t, FF_, D_);
  transpose_kernel<<<dim3(16, 16, L_), tb, 0, stream>>>(Wp, wpt, D_, D_);
  pack_bias_kernel<<<dim3(L_), dim3(512), 0, stream>>>(bq, bk, bv, bqkv);
  init_kernel<<<dim3(512), dim3(256), 0, stream>>>(xs, pe, x, pe_bf);

  dim3 blk(256);
  // P[l] = pe @ Wp[l] for all layers: M=512,N=512,K=512, z=6, bf16 out
  mgemm_kernel<64><<<dim3(8, 4, L_), blk, 0, stream>>>(
      pe_bf, wpt, nullptr, nullptr, pbuf, T_, D_, D_, 0, 1,
      (size_t)D_*D_, (size_t)T_*D_);

  for (int l = 0; l < L_; ++l){
    ln_kernel<0><<<dim3(MT_), blk, 0, stream>>>(x, ln1s + l*D_, ln1b + l*D_, h_bf);
    // QKV: M=4096, N=1536, K=512 -> bf16 qkv
    mgemm_kernel<128><<<dim3(12, 32, 1), blk, 0, stream>>>(
        h_bf, qkvt + (size_t)l*3*D_*D_, bqkv + l*3*D_, nullptr, qkv_bf,
        MT_, 3*D_, D_, 0, 1, 0, 0);
    attn_kernel<<<dim3(T_/CS_, H_, B_), blk, 0, stream>>>(
        qkv_bf, pbuf + (size_t)l*T_*D_, pbu + l*H_*DK_, pbv + l*H_*DK_, ob_bf);
    // O-proj: M=4096, N=512, K=512, resid -> f32 x
    mgemm_kernel<64><<<dim3(8, 32, 1), blk, 0, stream>>>(
        ob_bf, wot + (size_t)l*D_*D_, bo + l*D_, x, x, MT_, D_, D_, 0, 0, 0, 0);
    ln_kernel<0><<<dim3(MT_), blk, 0, stream>>>(x, ln2s + l*D_, ln2b + l*D_, h_bf);
    // FF1: M=4096, N=2048, K=512, relu -> bf16 ff
    mgemm_kernel<128><<<dim3(16, 32, 1), blk, 0, stream>>>(
        h_bf, w1t + (size_t)l*D_*FF_, b1 + l*FF_, nullptr, ff_bf,
        MT_, FF_, D_, 1, 1, 0, 0);
    // FF2: M=4096, N=512, K=2048, resid -> f32 x
    mgemm_kernel<64><<<dim3(8, 32, 1), blk, 0, stream>>>(
        ff_bf, w2t + (size_t)l*FF_*D_, b2 + l*D_, x, x, MT_, D_, FF_, 0, 0, 0, 0);
  }
  ln_kernel<1><<<dim3(MT_), blk, 0, stream>>>(x, lnfs, lnfb, d_out);
}

// Round 5
// 1344.911 us; speedup vs baseline: 3.9664x; 1.4517x over previous
//
#include <hip/hip_runtime.h>

// Problem constants (B,T,D,H,FF,L,CS,LC) = (8,512,512,8,2048,6,16,4)
#define B_ 8
#define T_ 512
#define D_ 512
#define H_ 8
#define FF_ 2048
#define L_ 6
#define CS_ 16
#define LC_ 4
#define DK_ 64
#define MT_ (B_*T_)   // 4096 rows

typedef unsigned short u16;  // raw bf16
typedef __attribute__((ext_vector_type(8))) short bf8_t;   // 8 x bf16 (4 VGPR)
typedef __attribute__((ext_vector_type(4))) float f4_t;    // 4 x f32 acc

__device__ __forceinline__ float bf2f(u16 u){
  union { unsigned int i; float f; } c; c.i = ((unsigned int)u) << 16; return c.f;
}
__device__ __forceinline__ u16 f2bf(float f){
  union { float f; unsigned int i; } c; c.f = f;
  unsigned int x = c.i;
  return (u16)((x + 0x7FFFu + ((x >> 16) & 1u)) >> 16);  // RNE
}

// ---------------- init: x = xs*sqrt(D) (f32), pe_bf = bf16(pos_emb) ----------
__global__ void init_kernel(const float* __restrict__ xs, const float* __restrict__ pe,
                            float* __restrict__ x, u16* __restrict__ pe_bf)
{
  int stride = gridDim.x * blockDim.x;
  int i0 = blockIdx.x * blockDim.x + threadIdx.x;
  const float s = 22.62741699796952f;  // sqrt(512)
  for (int i = i0; i < B_*T_*D_; i += stride) x[i] = xs[i] * s;
  for (int i = i0; i < T_*D_;    i += stride) pe_bf[i] = f2bf(pe[i]);
}

// ---------------- generic transpose+convert: in f32 [K][N] -> out bf16 [N][K]
// grid: (N/32, K/32, nmats); block (32,8)
__global__ void transpose_kernel(const float* __restrict__ in, u16* __restrict__ out,
                                 int K, int N)
{
  __shared__ float tile[32][33];
  int l = blockIdx.z;
  const float* src = in + (size_t)l * K * N;
  u16* dst = out + (size_t)l * N * K;
  int n0 = blockIdx.x * 32, k0 = blockIdx.y * 32;
  int tx = threadIdx.x, ty = threadIdx.y;
  #pragma unroll
  for (int i = 0; i < 4; ++i)
    tile[ty + i*8][tx] = src[(size_t)(k0 + ty + i*8) * N + n0 + tx];
  __syncthreads();
  #pragma unroll
  for (int i = 0; i < 4; ++i)
    dst[(size_t)(n0 + ty + i*8) * K + k0 + tx] = f2bf(tile[tx][ty + i*8]);
}

// ---------------- QKV packed transpose: out[l][n][k], n<512:Wq, <1024:Wk, else Wv
// grid: (1536/32, 512/32, 6); block (32,8)
__global__ void transpose_qkv_kernel(const float* __restrict__ Wq, const float* __restrict__ Wk,
                                     const float* __restrict__ Wv, u16* __restrict__ out)
{
  __shared__ float tile[32][33];
  int l = blockIdx.z;
  int n0 = blockIdx.x * 32, k0 = blockIdx.y * 32;
  const float* W = (n0 < 512) ? Wq : (n0 < 1024 ? Wk : Wv);
  int nn0 = n0 & 511;
  const float* src = W + (size_t)l * D_ * D_;
  u16* dst = out + (size_t)l * 3 * D_ * D_;
  int tx = threadIdx.x, ty = threadIdx.y;
  #pragma unroll
  for (int i = 0; i < 4; ++i)
    tile[ty + i*8][tx] = src[(size_t)(k0 + ty + i*8) * D_ + nn0 + tx];
  __syncthreads();
  #pragma unroll
  for (int i = 0; i < 4; ++i)
    dst[(size_t)(n0 + ty + i*8) * D_ + k0 + tx] = f2bf(tile[tx][ty + i*8]);
}

// ---------------- bias pack: bqkv[l][1536] -----------------------------------
__global__ void pack_bias_kernel(const float* __restrict__ bq, const float* __restrict__ bk,
                                 const float* __restrict__ bv, float* __restrict__ out)
{
  int l = blockIdx.x, t = threadIdx.x;  // 512 threads
  out[l*1536 + t]        = bq[l*512 + t];
  out[l*1536 + 512  + t] = bk[l*512 + t];
  out[l*1536 + 1024 + t] = bv[l*512 + t];
}

// ---------------- LayerNorm ---------------------------------------------------
// OUTMODE 0: write bf16 (workspace activation). OUTMODE 1: write f32 (final out)
template <int OUTMODE>
__global__ __launch_bounds__(256) void ln_kernel(const float* __restrict__ x,
    const float* __restrict__ g, const float* __restrict__ b, void* __restrict__ outp)
{
  int row = blockIdx.x;
  const float* xr = x + (size_t)row * D_;
  int t = threadIdx.x;
  float v0 = xr[t], v1 = xr[t + 256];
  float s = v0 + v1, s2 = v0*v0 + v1*v1;
  #pragma unroll
  for (int off = 32; off > 0; off >>= 1){ s += __shfl_down(s, off); s2 += __shfl_down(s2, off); }
  __shared__ float ps[4], ps2[4], mb[2];
  int w = t >> 6;
  if ((t & 63) == 0){ ps[w] = s; ps2[w] = s2; }
  __syncthreads();
  if (t == 0){
    float S = ps[0]+ps[1]+ps[2]+ps[3];
    float S2 = ps2[0]+ps2[1]+ps2[2]+ps2[3];
    float m = S * (1.0f / D_);
    float var = S2 * (1.0f / D_) - m*m;   // population var, matches jnp.var
    mb[0] = m; mb[1] = rsqrtf(var + 1e-5f);
  }
  __syncthreads();
  float m = mb[0], rs = mb[1];
  float o0 = (v0 - m) * rs * g[t]     + b[t];
  float o1 = (v1 - m) * rs * g[t+256] + b[t+256];
  if (OUTMODE == 1){
    float* outr = (float*)outp + (size_t)row * D_;
    outr[t] = o0; outr[t+256] = o1;
  } else {
    u16* outr = (u16*)outp + (size_t)row * D_;
    outr[t] = f2bf(o0); outr[t+256] = f2bf(o1);
  }
}

// ---------------- MFMA GEMM ---------------------------------------------------
// C[M][N] = A[M][K](bf16) @ Bt[N][K](bf16)^T  [+bias][relu][+resid], out f32/bf16
// tile: 128(M) x TN(N), BK=32; 256 threads = 4 waves, wave grid 2x2,
// wave sub-tile 64 x TN/2. grid: (N/TN, M/128, Z).
template <int TN>
__global__ __launch_bounds__(256) void mgemm_kernel(
    const u16* __restrict__ A, const u16* __restrict__ Bt,
    const float* __restrict__ bias, const float* __restrict__ resid,
    void* __restrict__ C, int M, int N, int K,
    int relu, int bf16out, size_t wstride, size_t cstride)
{
  constexpr int NT = TN / 32;            // 16-col tiles per wave sub-tile
  Bt += (size_t)blockIdx.z * wstride;
  size_t coff = (size_t)blockIdx.z * cstride;

  __shared__ u16 As[128 * 32];           // [m][k], 8 KB
  __shared__ u16 Bs[TN * 32];            // [n][k]

  int tid  = threadIdx.x;
  int wave = tid >> 6, lane = tid & 63;
  int wm = wave >> 1, wn = wave & 1;
  int fm = lane & 15, fq = lane >> 4;    // frag row, quad

  int m0 = blockIdx.y * 128, n0 = blockIdx.x * TN;

  f4_t acc[4][NT];
  #pragma unroll
  for (int i = 0; i < 4; ++i)
    #pragma unroll
    for (int j = 0; j < NT; ++j) acc[i][j] = (f4_t)0.0f;

  int srow = lane >> 2;                  // staging row-in-chunk (16 rows/chunk)
  int selem = (lane & 3) * 8;            // staging k-element offset

  for (int k0 = 0; k0 < K; k0 += 32){
    // stage A: 8 chunks of 16 rows; wave w does chunks 2w, 2w+1
    #pragma unroll
    for (int j = 0; j < 2; ++j){
      int c = wave * 2 + j;
      const u16* gp = A + (size_t)(m0 + c*16 + srow) * K + k0 + selem;
      u16* lp = &As[c * 512];
      __builtin_amdgcn_global_load_lds((const __attribute__((address_space(1))) void*)gp,
                                       (__attribute__((address_space(3))) void*)lp, 16, 0, 0);
    }
    // stage B: TN/16 chunks
    #pragma unroll
    for (int j = 0; j < TN/64; ++j){
      int c = wave * (TN/64) + j;
      const u16* gp = Bt + (size_t)(n0 + c*16 + srow) * K + k0 + selem;
      u16* lp = &Bs[c * 512];
      __builtin_amdgcn_global_load_lds((const __attribute__((address_space(1))) void*)gp,
                                       (__attribute__((address_space(3))) void*)lp, 16, 0, 0);
    }
    __syncthreads();

    bf8_t af[4], bf[NT];
    #pragma unroll
    for (int mi = 0; mi < 4; ++mi)
      af[mi] = *(const bf8_t*)&As[(wm*64 + mi*16 + fm) * 32 + fq*8];
    #pragma unroll
    for (int nj = 0; nj < NT; ++nj)
      bf[nj] = *(const bf8_t*)&Bs[(wn*(TN/2) + nj*16 + fm) * 32 + fq*8];
    #pragma unroll
    for (int mi = 0; mi < 4; ++mi)
      #pragma unroll
      for (int nj = 0; nj < NT; ++nj)
        acc[mi][nj] = __builtin_amdgcn_mfma_f32_16x16x32_bf16(af[mi], bf[nj], acc[mi][nj], 0, 0, 0);
    __syncthreads();
  }

  // epilogue: C/D layout col = lane&15, row = (lane>>4)*4 + reg  [m89]
  int rbase = m0 + wm*64, cbase = n0 + wn*(TN/2);
  #pragma unroll
  for (int mi = 0; mi < 4; ++mi){
    #pragma unroll
    for (int nj = 0; nj < NT; ++nj){
      int col = cbase + nj*16 + fm;
      float bia = bias ? bias[col] : 0.0f;
      #pragma unroll
      for (int r = 0; r < 4; ++r){
        int row = rbase + mi*16 + fq*4 + r;
        size_t idx = coff + (size_t)row * N + col;
        float val = acc[mi][nj][r] + bia;
        if (relu)  val = fmaxf(val, 0.0f);
        if (resid) val += resid[idx];
        if (bf16out) ((u16*)C)[idx] = f2bf(val);
        else         ((float*)C)[idx] = val;
      }
    }
  }
}

// ---------------- Fused chunked attention ------------------------------------
// qkv bf16 [4096][1536] (q|k|v each 512 cols), p bf16 [512][512],
// pbu/pbv f32 [512] (layer-folded), out bf16 [4096][512].
// LDS leading dims padded to 65 (odd) so lane-stride-64 accesses spread banks.
#define PD_ 65
__global__ __launch_bounds__(256) void attn_kernel(
    const u16* __restrict__ qkv, const u16* __restrict__ p,
    const float* __restrict__ pbu, const float* __restrict__ pbv,
    u16* __restrict__ o)
{
  int ci = blockIdx.x, h = blockIdx.y, b = blockIdx.z;
  int t0 = ci * CS_;
  int cb = ci - LC_; if (cb < 0) cb = 0;
  int c0 = cb * CS_;
  int ncol = (ci + 1) * CS_ - c0;   // 16..80
  __shared__ float qu[CS_][PD_], qv[CS_][PD_];
  __shared__ float buf[5*CS_][PD_];     // K tile -> P tile -> V tile
  __shared__ float sc[CS_][5*CS_+1];
  __shared__ float red[CS_][16];
  int tid = threadIdx.x;

  const u16* qbase = qkv + ((size_t)(b*T_ + t0)) * 1536 + h*DK_;
  for (int i = tid; i < CS_*DK_; i += 256){
    int r = i >> 6, d = i & 63;
    float qq = bf2f(qbase[(size_t)r * 1536 + d]);
    qu[r][d] = qq + pbu[h*DK_ + d];
    qv[r][d] = qq + pbv[h*DK_ + d];
  }
  const u16* kbase = qkv + ((size_t)(b*T_ + c0)) * 1536 + 512 + h*DK_;
  for (int i = tid; i < ncol*DK_; i += 256){
    int r = i >> 6, d = i & 63;
    buf[r][d] = bf2f(kbase[(size_t)r * 1536 + d]);
  }
  __syncthreads();
  const float scale = 0.125f;  // 1/sqrt(64)
  for (int i = tid; i < CS_*ncol; i += 256){
    int r = i / ncol, cc = i - r*ncol;
    float s = 0.f;
    #pragma unroll
    for (int d = 0; d < DK_; ++d) s += qu[r][d] * buf[cc][d];
    sc[r][cc] = s * scale;
  }
  __syncthreads();
  const u16* pbase = p + (size_t)c0 * D_ + h*DK_;
  for (int i = tid; i < ncol*DK_; i += 256){
    int r = i >> 6, d = i & 63;
    buf[r][d] = bf2f(pbase[(size_t)r * D_ + d]);
  }
  __syncthreads();
  for (int i = tid; i < CS_*ncol; i += 256){
    int r = i / ncol, cc = i - r*ncol;
    float s = 0.f;
    #pragma unroll
    for (int d = 0; d < DK_; ++d) s += qv[r][d] * buf[cc][d];
    sc[r][cc] += s * scale;
  }
  __syncthreads();
  const u16* vbase = qkv + ((size_t)(b*T_ + c0)) * 1536 + 1024 + h*DK_;
  for (int i = tid; i < ncol*DK_; i += 256){
    int r = i >> 6, d = i & 63;
    buf[r][d] = bf2f(vbase[(size_t)r * 1536 + d]);
  }
  // softmax (16 threads per row)
  int r = tid >> 4, j = tid & 15;
  float mx = -3.0e38f;
  for (int cc = j; cc < ncol; cc += 16) mx = fmaxf(mx, sc[r][cc]);
  red[r][j] = mx;
  __syncthreads();
  float m = red[r][0];
  #pragma unroll
  for (int t2 = 1; t2 < 16; ++t2) m = fmaxf(m, red[r][t2]);
  float sum = 0.f;
  for (int cc = j; cc < ncol; cc += 16){
    float e = __expf(sc[r][cc] - m);
    sc[r][cc] = e; sum += e;
  }
  __syncthreads();
  red[r][j] = sum;
  __syncthreads();
  float S = red[r][0];
  #pragma unroll
  for (int t2 = 1; t2 < 16; ++t2) S += red[r][t2];
  float inv = 1.0f / S;
  for (int cc = j; cc < ncol; cc += 16) sc[r][cc] *= inv;
  __syncthreads();
  u16* obase = o + ((size_t)(b*T_ + t0)) * D_ + h*DK_;
  for (int i = tid; i < CS_*DK_; i += 256){
    int rr = i >> 6, d = i & 63;
    float acc = 0.f;
    for (int cc = 0; cc < ncol; ++cc) acc += sc[rr][cc] * buf[cc][d];
    obase[(size_t)rr * D_ + d] = f2bf(acc);
  }
}

// ---------------- launcher ---------------------------------------------------
extern "C" void kernel_launch(void* const* d_in, const int* in_sizes, int n_in,
                              void* d_out, int out_size, void* d_ws, size_t ws_size,
                              hipStream_t stream)
{
  int s0 = (n_in >= 24) ? 0 : -1;
  const float* xs   = (const float*)d_in[0];
  const float* pe   = (const float*)d_in[1];
  const float* Wq   = (const float*)d_in[3  + s0];
  const float* bq   = (const float*)d_in[4  + s0];
  const float* Wk   = (const float*)d_in[5  + s0];
  const float* bk   = (const float*)d_in[6  + s0];
  const float* Wv   = (const float*)d_in[7  + s0];
  const float* bv   = (const float*)d_in[8  + s0];
  const float* Wo   = (const float*)d_in[9  + s0];
  const float* bo   = (const float*)d_in[10 + s0];
  const float* Wp   = (const float*)d_in[11 + s0];
  const float* pbu  = (const float*)d_in[12 + s0];
  const float* pbv  = (const float*)d_in[13 + s0];
  const float* ln1s = (const float*)d_in[14 + s0];
  const float* ln1b = (const float*)d_in[15 + s0];
  const float* ln2s = (const float*)d_in[16 + s0];
  const float* ln2b = (const float*)d_in[17 + s0];
  const float* W1   = (const float*)d_in[18 + s0];
  const float* b1   = (const float*)d_in[19 + s0];
  const float* W2   = (const float*)d_in[20 + s0];
  const float* b2   = (const float*)d_in[21 + s0];
  const float* lnfs = (const float*)d_in[22 + s0];
  const float* lnfb = (const float*)d_in[23 + s0];

  float* ws = (float*)d_ws;
  size_t cur = 0;
  float* x      = ws + cur;            cur += (size_t)MT_*D_;        // 2,097,152
  u16*   region = (u16*)(ws + cur);    cur += (size_t)MT_*FF_/2;     // 8M u16: qkv(6M)|ff(8M) alias
  u16*   qkv_bf = region;
  u16*   ff_bf  = region;
  u16*   h_bf   = (u16*)(ws + cur);    cur += (size_t)MT_*D_/2;
  u16*   ob_bf  = (u16*)(ws + cur);    cur += (size_t)MT_*D_/2;
  u16*   pe_bf  = (u16*)(ws + cur);    cur += (size_t)T_*D_/2;
  u16*   pbuf   = (u16*)(ws + cur);    cur += (size_t)L_*T_*D_/2;
  u16*   qkvt   = (u16*)(ws + cur);    cur += (size_t)L_*3*D_*D_/2;
  u16*   wot    = (u16*)(ws + cur);    cur += (size_t)L_*D_*D_/2;
  u16*   w1t    = (u16*)(ws + cur);    cur += (size_t)L_*D_*FF_/2;
  u16*   w2t    = (u16*)(ws + cur);    cur += (size_t)L_*FF_*D_/2;
  u16*   wpt    = (u16*)(ws + cur);    cur += (size_t)L_*D_*D_/2;
  float* bqkv   = ws + cur;            cur += (size_t)L_*3*D_;
  // total ~19.5M floats ~78 MB

  dim3 tb(32, 8);
  // weight conversion (every launch; ws is re-poisoned by harness)
  transpose_qkv_kernel<<<dim3(48, 16, L_), tb, 0, stream>>>(Wq, Wk, Wv, qkvt);
  transpose_kernel<<<dim3(16, 16, L_), tb, 0, stream>>>(Wo, wot, D_, D_);
  transpose_kernel<<<dim3(64, 16, L_), tb, 0, stream>>>(W1, w1t, D_, FF_);
  transpose_kernel<<<dim3(16, 64, L_), tb, 0, stream>>>(W2, w2t, FF_, D_);
  transpose_kernel<<<dim3(16, 16, L_), tb, 0, stream>>>(Wp, wpt, D_, D_);
  pack_bias_kernel<<<dim3(L_), dim3(512), 0, stream>>>(bq, bk, bv, bqkv);
  init_kernel<<<dim3(512), dim3(256), 0, stream>>>(xs, pe, x, pe_bf);

  dim3 blk(256);
  // P[l] = pe @ Wp[l] for all layers: M=512,N=512,K=512, z=6, bf16 out
  mgemm_kernel<64><<<dim3(8, 4, L_), blk, 0, stream>>>(
      pe_bf, wpt, nullptr, nullptr, pbuf, T_, D_, D_, 0, 1,
      (size_t)D_*D_, (size_t)T_*D_);

  for (int l = 0; l < L_; ++l){
    ln_kernel<0><<<dim3(MT_), blk, 0, stream>>>(x, ln1s + l*D_, ln1b + l*D_, h_bf);
    // QKV: M=4096, N=1536, K=512 -> bf16 qkv
    mgemm_kernel<128><<<dim3(12, 32, 1), blk, 0, stream>>>(
        h_bf, qkvt + (size_t)l*3*D_*D_, bqkv + l*3*D_, nullptr, qkv_bf,
        MT_, 3*D_, D_, 0, 1, 0, 0);
    attn_kernel<<<dim3(T_/CS_, H_, B_), blk, 0, stream>>>(
        qkv_bf, pbuf + (size_t)l*T_*D_, pbu + l*H_*DK_, pbv + l*H_*DK_, ob_bf);
    // O-proj: M=4096, N=512, K=512, resid -> f32 x
    mgemm_kernel<64><<<dim3(8, 32, 1), blk, 0, stream>>>(
        ob_bf, wot + (size_t)l*D_*D_, bo + l*D_, x, x, MT_, D_, D_, 0, 0, 0, 0);
    ln_kernel<0><<<dim3(MT_), blk, 0, stream>>>(x, ln2s + l*D_, ln2b + l*D_, h_bf);
    // FF1: M=4096, N=2048, K=512, relu -> bf16 ff
    mgemm_kernel<128><<<dim3(16, 32, 1), blk, 0, stream>>>(
        h_bf, w1t + (size_t)l*D_*FF_, b1 + l*FF_, nullptr, ff_bf,
        MT_, FF_, D_, 1, 1, 0, 0);
    // FF2: M=4096, N=512, K=2048, resid -> f32 x
    mgemm_kernel<64><<<dim3(8, 32, 1), blk, 0, stream>>>(
        ff_bf, w2t + (size_t)l*FF_*D_, b2 + l*D_, x, x, MT_, D_, FF_, 0, 0, 0, 0);
  }
  ln_kernel<1><<<dim3(MT_), blk, 0, stream>>>(x, lnfs, lnfb, d_out);
}

// Round 6
// 1036.781 us; speedup vs baseline: 5.1452x; 1.2972x over previous
//
#include <hip/hip_runtime.h>

// Problem constants (B,T,D,H,FF,L,CS,LC) = (8,512,512,8,2048,6,16,4)
#define B_ 8
#define T_ 512
#define D_ 512
#define H_ 8
#define FF_ 2048
#define L_ 6
#define CS_ 16
#define LC_ 4
#define DK_ 64
#define MT_ (B_*T_)   // 4096 rows

typedef unsigned short u16;  // raw bf16
typedef __attribute__((ext_vector_type(8))) short bf8_t;   // 8 x bf16 (4 VGPR)
typedef __attribute__((ext_vector_type(4))) float f4_t;    // 4 x f32 acc

__device__ __forceinline__ float bf2f(u16 u){
  union { unsigned int i; float f; } c; c.i = ((unsigned int)u) << 16; return c.f;
}
__device__ __forceinline__ u16 f2bf(float f){
  union { float f; unsigned int i; } c; c.f = f;
  unsigned int x = c.i;
  return (u16)((x + 0x7FFFu + ((x >> 16) & 1u)) >> 16);  // RNE
}

// ---------------- init: x = xs*sqrt(D) (f32), pe_bf = bf16(pos_emb) ----------
__global__ void init_kernel(const float* __restrict__ xs, const float* __restrict__ pe,
                            float* __restrict__ x, u16* __restrict__ pe_bf)
{
  int stride = gridDim.x * blockDim.x;
  int i0 = blockIdx.x * blockDim.x + threadIdx.x;
  const float s = 22.62741699796952f;  // sqrt(512)
  for (int i = i0; i < B_*T_*D_; i += stride) x[i] = xs[i] * s;
  for (int i = i0; i < T_*D_;    i += stride) pe_bf[i] = f2bf(pe[i]);
}

// ---------------- generic transpose+convert: in f32 [K][N] -> out bf16 [N][K]
// grid: (N/32, K/32, nmats); block (32,8)
__global__ void transpose_kernel(const float* __restrict__ in, u16* __restrict__ out,
                                 int K, int N)
{
  __shared__ float tile[32][33];
  int l = blockIdx.z;
  const float* src = in + (size_t)l * K * N;
  u16* dst = out + (size_t)l * N * K;
  int n0 = blockIdx.x * 32, k0 = blockIdx.y * 32;
  int tx = threadIdx.x, ty = threadIdx.y;
  #pragma unroll
  for (int i = 0; i < 4; ++i)
    tile[ty + i*8][tx] = src[(size_t)(k0 + ty + i*8) * N + n0 + tx];
  __syncthreads();
  #pragma unroll
  for (int i = 0; i < 4; ++i)
    dst[(size_t)(n0 + ty + i*8) * K + k0 + tx] = f2bf(tile[tx][ty + i*8]);
}

// ---------------- QKV packed transpose: out[l][n][k], n<512:Wq, <1024:Wk, else Wv
// grid: (1536/32, 512/32, 6); block (32,8)
__global__ void transpose_qkv_kernel(const float* __restrict__ Wq, const float* __restrict__ Wk,
                                     const float* __restrict__ Wv, u16* __restrict__ out)
{
  __shared__ float tile[32][33];
  int l = blockIdx.z;
  int n0 = blockIdx.x * 32, k0 = blockIdx.y * 32;
  const float* W = (n0 < 512) ? Wq : (n0 < 1024 ? Wk : Wv);
  int nn0 = n0 & 511;
  const float* src = W + (size_t)l * D_ * D_;
  u16* dst = out + (size_t)l * 3 * D_ * D_;
  int tx = threadIdx.x, ty = threadIdx.y;
  #pragma unroll
  for (int i = 0; i < 4; ++i)
    tile[ty + i*8][tx] = src[(size_t)(k0 + ty + i*8) * D_ + nn0 + tx];
  __syncthreads();
  #pragma unroll
  for (int i = 0; i < 4; ++i)
    dst[(size_t)(n0 + ty + i*8) * D_ + k0 + tx] = f2bf(tile[tx][ty + i*8]);
}

// ---------------- bias pack: bqkv[l][1536] -----------------------------------
__global__ void pack_bias_kernel(const float* __restrict__ bq, const float* __restrict__ bk,
                                 const float* __restrict__ bv, float* __restrict__ out)
{
  int l = blockIdx.x, t = threadIdx.x;  // 512 threads
  out[l*1536 + t]        = bq[l*512 + t];
  out[l*1536 + 512  + t] = bk[l*512 + t];
  out[l*1536 + 1024 + t] = bv[l*512 + t];
}

// ---------------- LayerNorm ---------------------------------------------------
// OUTMODE 0: write bf16 (workspace activation). OUTMODE 1: write f32 (final out)
template <int OUTMODE>
__global__ __launch_bounds__(256) void ln_kernel(const float* __restrict__ x,
    const float* __restrict__ g, const float* __restrict__ b, void* __restrict__ outp)
{
  int row = blockIdx.x;
  const float* xr = x + (size_t)row * D_;
  int t = threadIdx.x;
  float v0 = xr[t], v1 = xr[t + 256];
  float s = v0 + v1, s2 = v0*v0 + v1*v1;
  #pragma unroll
  for (int off = 32; off > 0; off >>= 1){ s += __shfl_down(s, off); s2 += __shfl_down(s2, off); }
  __shared__ float ps[4], ps2[4], mb[2];
  int w = t >> 6;
  if ((t & 63) == 0){ ps[w] = s; ps2[w] = s2; }
  __syncthreads();
  if (t == 0){
    float S = ps[0]+ps[1]+ps[2]+ps[3];
    float S2 = ps2[0]+ps2[1]+ps2[2]+ps2[3];
    float m = S * (1.0f / D_);
    float var = S2 * (1.0f / D_) - m*m;   // population var, matches jnp.var
    mb[0] = m; mb[1] = rsqrtf(var + 1e-5f);
  }
  __syncthreads();
  float m = mb[0], rs = mb[1];
  float o0 = (v0 - m) * rs * g[t]     + b[t];
  float o1 = (v1 - m) * rs * g[t+256] + b[t+256];
  if (OUTMODE == 1){
    float* outr = (float*)outp + (size_t)row * D_;
    outr[t] = o0; outr[t+256] = o1;
  } else {
    u16* outr = (u16*)outp + (size_t)row * D_;
    outr[t] = f2bf(o0); outr[t+256] = f2bf(o1);
  }
}

// ---------------- MFMA GEMM ---------------------------------------------------
// C[M][N] = A[M][K](bf16) @ Bt[N][K](bf16)^T  [+bias][relu][+resid], out f32/bf16
// tile: 128(M) x TN(N), BK=32; 256 threads = 4 waves, wave grid 2x2,
// wave sub-tile 64 x TN/2. grid: (N/TN, M/128, Z).
template <int TN>
__global__ __launch_bounds__(256) void mgemm_kernel(
    const u16* __restrict__ A, const u16* __restrict__ Bt,
    const float* __restrict__ bias, const float* __restrict__ resid,
    void* __restrict__ C, int M, int N, int K,
    int relu, int bf16out, size_t wstride, size_t cstride)
{
  constexpr int NT = TN / 32;            // 16-col tiles per wave sub-tile
  Bt += (size_t)blockIdx.z * wstride;
  size_t coff = (size_t)blockIdx.z * cstride;

  __shared__ u16 As[128 * 32];           // [m][k], 8 KB
  __shared__ u16 Bs[TN * 32];            // [n][k]

  int tid  = threadIdx.x;
  int wave = tid >> 6, lane = tid & 63;
  int wm = wave >> 1, wn = wave & 1;
  int fm = lane & 15, fq = lane >> 4;    // frag row, quad

  int m0 = blockIdx.y * 128, n0 = blockIdx.x * TN;

  f4_t acc[4][NT];
  #pragma unroll
  for (int i = 0; i < 4; ++i)
    #pragma unroll
    for (int j = 0; j < NT; ++j) acc[i][j] = (f4_t)0.0f;

  int srow = lane >> 2;                  // staging row-in-chunk (16 rows/chunk)
  int selem = (lane & 3) << 3;           // staging k-element offset

  for (int k0 = 0; k0 < K; k0 += 32){
    #pragma unroll
    for (int j = 0; j < 2; ++j){
      int c = wave * 2 + j;
      const u16* gp = A + (size_t)(m0 + c*16 + srow) * K + k0 + selem;
      u16* lp = &As[c * 512];
      __builtin_amdgcn_global_load_lds((const __attribute__((address_space(1))) void*)gp,
                                       (__attribute__((address_space(3))) void*)lp, 16, 0, 0);
    }
    #pragma unroll
    for (int j = 0; j < TN/64; ++j){
      int c = wave * (TN/64) + j;
      const u16* gp = Bt + (size_t)(n0 + c*16 + srow) * K + k0 + selem;
      u16* lp = &Bs[c * 512];
      __builtin_amdgcn_global_load_lds((const __attribute__((address_space(1))) void*)gp,
                                       (__attribute__((address_space(3))) void*)lp, 16, 0, 0);
    }
    __syncthreads();

    bf8_t af[4], bf[NT];
    #pragma unroll
    for (int mi = 0; mi < 4; ++mi)
      af[mi] = *(const bf8_t*)&As[(wm*64 + mi*16 + fm) * 32 + fq*8];
    #pragma unroll
    for (int nj = 0; nj < NT; ++nj)
      bf[nj] = *(const bf8_t*)&Bs[(wn*(TN/2) + nj*16 + fm) * 32 + fq*8];
    #pragma unroll
    for (int mi = 0; mi < 4; ++mi)
      #pragma unroll
      for (int nj = 0; nj < NT; ++nj)
        acc[mi][nj] = __builtin_amdgcn_mfma_f32_16x16x32_bf16(af[mi], bf[nj], acc[mi][nj], 0, 0, 0);
    __syncthreads();
  }

  // epilogue: C/D layout col = lane&15, row = (lane>>4)*4 + reg
  int rbase = m0 + wm*64, cbase = n0 + wn*(TN/2);
  #pragma unroll
  for (int mi = 0; mi < 4; ++mi){
    #pragma unroll
    for (int nj = 0; nj < NT; ++nj){
      int col = cbase + nj*16 + fm;
      float bia = bias ? bias[col] : 0.0f;
      #pragma unroll
      for (int r = 0; r < 4; ++r){
        int row = rbase + mi*16 + fq*4 + r;
        size_t idx = coff + (size_t)row * N + col;
        float val = acc[mi][nj][r] + bia;
        if (relu)  val = fmaxf(val, 0.0f);
        if (resid) val += resid[idx];
        if (bf16out) ((u16*)C)[idx] = f2bf(val);
        else         ((float*)C)[idx] = val;
      }
    }
  }
}

// ---------------- Fused chunked attention (single-wave MFMA) ------------------
// block = 1 wave (64 thr), grid (32 chunks, 8 heads, 8 batch).
// qkv bf16 [4096][1536] (q|k|v), p bf16 [512][512], pbu/pbv f32 (layer-folded),
// out bf16 [4096][512].
// Always loads the full 80-row K/P/V window (c0+80 <= 512 always in-bounds);
// cols >= ncol masked to -inf/0 at softmax.
__global__ __launch_bounds__(64) void attn_kernel(
    const u16* __restrict__ qkv, const u16* __restrict__ p,
    const float* __restrict__ pbu, const float* __restrict__ pbv,
    u16* __restrict__ o)
{
  int ci = blockIdx.x, h = blockIdx.y, b = blockIdx.z;
  int t0 = ci * CS_;
  int cb = ci - LC_; if (cb < 0) cb = 0;
  int c0 = cb * CS_;
  int ncol = (ci + 1) * CS_ - c0;   // 16..80, multiple of 16

  __shared__ u16 smem[15648];       // 31,296 B
  u16* qu = smem;                         // [16][64] bf16
  u16* qv = smem + 1024;                  // [16][64]
  u16* kp = smem + 2048;                  // [80][64] bf16  (K tile, [n][k])
  u16* pp = smem + 2048 + 5120;           // [80][64] bf16  (P tile, [n][k])
  float* vf  = (float*)(smem + 2048);     // [80][64] f32   (aliases kp+pp, used after)
  float* psf = (float*)(smem + 12288);    // [16][105] f32  (probabilities)

  int lane = threadIdx.x;
  int fm = lane & 15, fq = lane >> 4;

  // ---- async stage K and P tiles (full 80 rows) ----
  const u16* kbase = qkv + ((size_t)(b*T_ + c0)) * 1536 + 512 + h*DK_;
  const u16* pbase = p + (size_t)c0 * D_ + h*DK_;
  int srow8 = lane >> 3, scol = (lane & 7) << 3;
  #pragma unroll
  for (int c = 0; c < 10; ++c){
    const u16* gk = kbase + (size_t)(c*8 + srow8) * 1536 + scol;
    __builtin_amdgcn_global_load_lds((const __attribute__((address_space(1))) void*)gk,
        (__attribute__((address_space(3))) void*)(kp + c*512 + lane*8), 16, 0, 0);
    const u16* gp = pbase + (size_t)(c*8 + srow8) * D_ + scol;
    __builtin_amdgcn_global_load_lds((const __attribute__((address_space(1))) void*)gp,
        (__attribute__((address_space(3))) void*)(pp + c*512 + lane*8), 16, 0, 0);
  }
  // ---- qu/qv = bf16(q + pbu/pbv) ----
  const u16* qbase = qkv + ((size_t)(b*T_ + t0)) * 1536 + h*DK_;
  #pragma unroll
  for (int it = 0; it < 4; ++it){
    int i = it*256 + lane*4; int r = i >> 6; int d = i & 63;
    ushort4 w = *(const ushort4*)(qbase + (size_t)r * 1536 + d);
    float4 bu = *(const float4*)(pbu + h*DK_ + d);
    float4 bv = *(const float4*)(pbv + h*DK_ + d);
    ushort4 ou, ov;
    ou.x = f2bf(bf2f(w.x) + bu.x); ou.y = f2bf(bf2f(w.y) + bu.y);
    ou.z = f2bf(bf2f(w.z) + bu.z); ou.w = f2bf(bf2f(w.w) + bu.w);
    ov.x = f2bf(bf2f(w.x) + bv.x); ov.y = f2bf(bf2f(w.y) + bv.y);
    ov.z = f2bf(bf2f(w.z) + bv.z); ov.w = f2bf(bf2f(w.w) + bv.w);
    *(ushort4*)(qu + r*64 + d) = ou;
    *(ushort4*)(qv + r*64 + d) = ov;
  }
  __syncthreads();

  // ---- scores: 5 n-tiles x (2 K-steps x (K-tile + P-tile)) MFMAs ----
  bf8_t au0 = *(const bf8_t*)(qu + fm*64 + fq*8);
  bf8_t au1 = *(const bf8_t*)(qu + fm*64 + 32 + fq*8);
  bf8_t av0 = *(const bf8_t*)(qv + fm*64 + fq*8);
  bf8_t av1 = *(const bf8_t*)(qv + fm*64 + 32 + fq*8);
  f4_t acc[5];
  #pragma unroll
  for (int nt = 0; nt < 5; ++nt) acc[nt] = (f4_t)0.0f;
  #pragma unroll
  for (int nt = 0; nt < 5; ++nt){
    const u16* kr = kp + (nt*16 + fm)*64;
    const u16* pr = pp + (nt*16 + fm)*64;
    bf8_t bk0 = *(const bf8_t*)(kr + fq*8);
    bf8_t bk1 = *(const bf8_t*)(kr + 32 + fq*8);
    bf8_t bp0 = *(const bf8_t*)(pr + fq*8);
    bf8_t bp1 = *(const bf8_t*)(pr + 32 + fq*8);
    f4_t a = acc[nt];
    a = __builtin_amdgcn_mfma_f32_16x16x32_bf16(au0, bk0, a, 0, 0, 0);
    a = __builtin_amdgcn_mfma_f32_16x16x32_bf16(au1, bk1, a, 0, 0, 0);
    a = __builtin_amdgcn_mfma_f32_16x16x32_bf16(av0, bp0, a, 0, 0, 0);
    a = __builtin_amdgcn_mfma_f32_16x16x32_bf16(av1, bp1, a, 0, 0, 0);
    acc[nt] = a;
  }

  // ---- softmax in C-layout regs: col s = nt*16+fm, row t = fq*4+r ----
  const float scale = 0.125f;  // 1/sqrt(64)
  float mx[4], sm[4];
  float e[5][4];
  #pragma unroll
  for (int r = 0; r < 4; ++r) mx[r] = -3.0e38f;
  #pragma unroll
  for (int nt = 0; nt < 5; ++nt){
    bool valid = (nt*16 + fm) < ncol;
    #pragma unroll
    for (int r = 0; r < 4; ++r){
      float v = valid ? acc[nt][r] : -3.0e38f;
      mx[r] = fmaxf(mx[r], v);
    }
  }
  #pragma unroll
  for (int r = 0; r < 4; ++r){
    #pragma unroll
    for (int m = 1; m < 16; m <<= 1) mx[r] = fmaxf(mx[r], __shfl_xor(mx[r], m));
    sm[r] = 0.0f;
  }
  #pragma unroll
  for (int nt = 0; nt < 5; ++nt){
    bool valid = (nt*16 + fm) < ncol;
    #pragma unroll
    for (int r = 0; r < 4; ++r){
      float ev = valid ? __expf((acc[nt][r] - mx[r]) * scale) : 0.0f;
      e[nt][r] = ev; sm[r] += ev;
    }
  }
  #pragma unroll
  for (int r = 0; r < 4; ++r){
    #pragma unroll
    for (int m = 1; m < 16; m <<= 1) sm[r] += __shfl_xor(sm[r], m);
    sm[r] = 1.0f / sm[r];
  }
  // write probabilities to LDS [16][105]
  #pragma unroll
  for (int nt = 0; nt < 5; ++nt)
    #pragma unroll
    for (int r = 0; r < 4; ++r)
      psf[(fq*4 + r)*105 + nt*16 + fm] = e[nt][r] * sm[r];
  __syncthreads();

  // ---- V tile -> f32 LDS (aliases dead K/P region) ----
  const u16* vbase = qkv + ((size_t)(b*T_ + c0)) * 1536 + 1024 + h*DK_;
  #pragma unroll
  for (int it = 0; it < 20; ++it){
    int i = it*256 + lane*4; int s = i >> 6; int d = i & 63;
    ushort4 w = *(const ushort4*)(vbase + (size_t)s * 1536 + d);
    float4 f; f.x = bf2f(w.x); f.y = bf2f(w.y); f.z = bf2f(w.z); f.w = bf2f(w.w);
    *(float4*)(vf + s*64 + d) = f;
  }
  __syncthreads();

  // ---- O = P @ V : lane handles row t=fm, cols [fq*16, fq*16+16) ----
  float oacc[16];
  #pragma unroll
  for (int ii = 0; ii < 16; ++ii) oacc[ii] = 0.0f;
  const float* psr = psf + fm*105;
  const float* vcol = vf + fq*16;
  for (int s = 0; s < 80; ++s){
    float pv = psr[s];
    const float* vr = vcol + s*64;
    float4 v0 = *(const float4*)(vr);
    float4 v1 = *(const float4*)(vr + 4);
    float4 v2 = *(const float4*)(vr + 8);
    float4 v3 = *(const float4*)(vr + 12);
    oacc[0]  += pv*v0.x; oacc[1]  += pv*v0.y; oacc[2]  += pv*v0.z; oacc[3]  += pv*v0.w;
    oacc[4]  += pv*v1.x; oacc[5]  += pv*v1.y; oacc[6]  += pv*v1.z; oacc[7]  += pv*v1.w;
    oacc[8]  += pv*v2.x; oacc[9]  += pv*v2.y; oacc[10] += pv*v2.z; oacc[11] += pv*v2.w;
    oacc[12] += pv*v3.x; oacc[13] += pv*v3.y; oacc[14] += pv*v3.z; oacc[15] += pv*v3.w;
  }
  u16* ob = o + ((size_t)(b*T_ + t0 + fm)) * D_ + h*DK_ + fq*16;
  #pragma unroll
  for (int q4 = 0; q4 < 4; ++q4){
    ushort4 w;
    w.x = f2bf(oacc[q4*4+0]); w.y = f2bf(oacc[q4*4+1]);
    w.z = f2bf(oacc[q4*4+2]); w.w = f2bf(oacc[q4*4+3]);
    *(ushort4*)(ob + q4*4) = w;
  }
}

// ---------------- launcher ---------------------------------------------------
extern "C" void kernel_launch(void* const* d_in, const int* in_sizes, int n_in,
                              void* d_out, int out_size, void* d_ws, size_t ws_size,
                              hipStream_t stream)
{
  int s0 = (n_in >= 24) ? 0 : -1;
  const float* xs   = (const float*)d_in[0];
  const float* pe   = (const float*)d_in[1];
  const float* Wq   = (const float*)d_in[3  + s0];
  const float* bq   = (const float*)d_in[4  + s0];
  const float* Wk   = (const float*)d_in[5  + s0];
  const float* bk   = (const float*)d_in[6  + s0];
  const float* Wv   = (const float*)d_in[7  + s0];
  const float* bv   = (const float*)d_in[8  + s0];
  const float* Wo   = (const float*)d_in[9  + s0];
  const float* bo   = (const float*)d_in[10 + s0];
  const float* Wp   = (const float*)d_in[11 + s0];
  const float* pbu  = (const float*)d_in[12 + s0];
  const float* pbv  = (const float*)d_in[13 + s0];
  const float* ln1s = (const float*)d_in[14 + s0];
  const float* ln1b = (const float*)d_in[15 + s0];
  const float* ln2s = (const float*)d_in[16 + s0];
  const float* ln2b = (const float*)d_in[17 + s0];
  const float* W1   = (const float*)d_in[18 + s0];
  const float* b1   = (const float*)d_in[19 + s0];
  const float* W2   = (const float*)d_in[20 + s0];
  const float* b2   = (const float*)d_in[21 + s0];
  const float* lnfs = (const float*)d_in[22 + s0];
  const float* lnfb = (const float*)d_in[23 + s0];

  float* ws = (float*)d_ws;
  size_t cur = 0;
  float* x      = ws + cur;            cur += (size_t)MT_*D_;        // 2,097,152
  u16*   region = (u16*)(ws + cur);    cur += (size_t)MT_*FF_/2;     // qkv(6M u16)|ff(8M u16) alias
  u16*   qkv_bf = region;
  u16*   ff_bf  = region;
  u16*   h_bf   = (u16*)(ws + cur);    cur += (size_t)MT_*D_/2;
  u16*   ob_bf  = (u16*)(ws + cur);    cur += (size_t)MT_*D_/2;
  u16*   pe_bf  = (u16*)(ws + cur);    cur += (size_t)T_*D_/2;
  u16*   pbuf   = (u16*)(ws + cur);    cur += (size_t)L_*T_*D_/2;
  u16*   qkvt   = (u16*)(ws + cur);    cur += (size_t)L_*3*D_*D_/2;
  u16*   wot    = (u16*)(ws + cur);    cur += (size_t)L_*D_*D_/2;
  u16*   w1t    = (u16*)(ws + cur);    cur += (size_t)L_*D_*FF_/2;
  u16*   w2t    = (u16*)(ws + cur);    cur += (size_t)L_*FF_*D_/2;
  u16*   wpt    = (u16*)(ws + cur);    cur += (size_t)L_*D_*D_/2;
  float* bqkv   = ws + cur;            cur += (size_t)L_*3*D_;
  // total ~19.5M floats ~78 MB

  dim3 tb(32, 8);
  transpose_qkv_kernel<<<dim3(48, 16, L_), tb, 0, stream>>>(Wq, Wk, Wv, qkvt);
  transpose_kernel<<<dim3(16, 16, L_), tb, 0, stream>>>(Wo, wot, D_, D_);
  transpose_kernel<<<dim3(64, 16, L_), tb, 0, stream>>>(W1, w1t, D_, FF_);
  transpose_kernel<<<dim3(16, 64, L_), tb, 0, stream>>>(W2, w2t, FF_, D_);
  transpose_kernel<<<dim3(16, 16, L_), tb, 0, stream>>>(Wp, wpt, D_, D_);
  pack_bias_kernel<<<dim3(L_), dim3(512), 0, stream>>>(bq, bk, bv, bqkv);
  init_kernel<<<dim3(512), dim3(256), 0, stream>>>(xs, pe, x, pe_bf);

  dim3 blk(256);
  // P[l] = pe @ Wp[l] for all layers: M=512,N=512,K=512, z=6, bf16 out
  mgemm_kernel<64><<<dim3(8, 4, L_), blk, 0, stream>>>(
      pe_bf, wpt, nullptr, nullptr, pbuf, T_, D_, D_, 0, 1,
      (size_t)D_*D_, (size_t)T_*D_);

  for (int l = 0; l < L_; ++l){
    ln_kernel<0><<<dim3(MT_), blk, 0, stream>>>(x, ln1s + l*D_, ln1b + l*D_, h_bf);
    // QKV: M=4096, N=1536, K=512 -> bf16 qkv
    mgemm_kernel<128><<<dim3(12, 32, 1), blk, 0, stream>>>(
        h_bf, qkvt + (size_t)l*3*D_*D_, bqkv + l*3*D_, nullptr, qkv_bf,
        MT_, 3*D_, D_, 0, 1, 0, 0);
    attn_kernel<<<dim3(T_/CS_, H_, B_), dim3(64), 0, stream>>>(
        qkv_bf, pbuf + (size_t)l*T_*D_, pbu + l*H_*DK_, pbv + l*H_*DK_, ob_bf);
    // O-proj: M=4096, N=512, K=512, resid -> f32 x
    mgemm_kernel<64><<<dim3(8, 32, 1), blk, 0, stream>>>(
        ob_bf, wot + (size_t)l*D_*D_, bo + l*D_, x, x, MT_, D_, D_, 0, 0, 0, 0);
    ln_kernel<0><<<dim3(MT_), blk, 0, stream>>>(x, ln2s + l*D_, ln2b + l*D_, h_bf);
    // FF1: M=4096, N=2048, K=512, relu -> bf16 ff
    mgemm_kernel<128><<<dim3(16, 32, 1), blk, 0, stream>>>(
        h_bf, w1t + (size_t)l*D_*FF_, b1 + l*FF_, nullptr, ff_bf,
        MT_, FF_, D_, 1, 1, 0, 0);
    // FF2: M=4096, N=512, K=2048, resid -> f32 x
    mgemm_kernel<64><<<dim3(8, 32, 1), blk, 0, stream>>>(
        ff_bf, w2t + (size_t)l*FF_*D_, b2 + l*D_, x, x, MT_, D_, FF_, 0, 0, 0, 0);
  }
  ln_kernel<1><<<dim3(MT_), blk, 0, stream>>>(x, lnfs, lnfb, d_out);
}

// Round 7
// 978.596 us; speedup vs baseline: 5.4511x; 1.0595x over previous
//
#include <hip/hip_runtime.h>

// Problem constants (B,T,D,H,FF,L,CS,LC) = (8,512,512,8,2048,6,16,4)
#define B_ 8
#define T_ 512
#define D_ 512
#define H_ 8
#define FF_ 2048
#define L_ 6
#define CS_ 16
#define LC_ 4
#define DK_ 64
#define MT_ (B_*T_)   // 4096 rows

typedef unsigned short u16;  // raw bf16
typedef __attribute__((ext_vector_type(8))) short bf8_t;   // 8 x bf16 (4 VGPR)
typedef __attribute__((ext_vector_type(4))) float f4_t;    // 4 x f32 acc

__device__ __forceinline__ float bf2f(u16 u){
  union { unsigned int i; float f; } c; c.i = ((unsigned int)u) << 16; return c.f;
}
__device__ __forceinline__ u16 f2bf(float f){
  union { float f; unsigned int i; } c; c.f = f;
  unsigned int x = c.i;
  return (u16)((x + 0x7FFFu + ((x >> 16) & 1u)) >> 16);  // RNE
}
__device__ __forceinline__ void ld_lds16(const u16* gp, u16* lp){
  __builtin_amdgcn_global_load_lds((const __attribute__((address_space(1))) void*)gp,
                                   (__attribute__((address_space(3))) void*)lp, 16, 0, 0);
}

// ---------------- init: x = xs*sqrt(D) (f32), pe_bf = bf16(pos_emb) ----------
__global__ void init_kernel(const float* __restrict__ xs, const float* __restrict__ pe,
                            float* __restrict__ x, u16* __restrict__ pe_bf)
{
  int stride = gridDim.x * blockDim.x;
  int i0 = blockIdx.x * blockDim.x + threadIdx.x;
  const float s = 22.62741699796952f;  // sqrt(512)
  for (int i = i0; i < B_*T_*D_; i += stride) x[i] = xs[i] * s;
  for (int i = i0; i < T_*D_;    i += stride) pe_bf[i] = f2bf(pe[i]);
}

// ---------------- generic transpose+convert: in f32 [K][N] -> out bf16 [N][K]
__global__ void transpose_kernel(const float* __restrict__ in, u16* __restrict__ out,
                                 int K, int N)
{
  __shared__ float tile[32][33];
  int l = blockIdx.z;
  const float* src = in + (size_t)l * K * N;
  u16* dst = out + (size_t)l * N * K;
  int n0 = blockIdx.x * 32, k0 = blockIdx.y * 32;
  int tx = threadIdx.x, ty = threadIdx.y;
  #pragma unroll
  for (int i = 0; i < 4; ++i)
    tile[ty + i*8][tx] = src[(size_t)(k0 + ty + i*8) * N + n0 + tx];
  __syncthreads();
  #pragma unroll
  for (int i = 0; i < 4; ++i)
    dst[(size_t)(n0 + ty + i*8) * K + k0 + tx] = f2bf(tile[tx][ty + i*8]);
}

// ---------------- QKV packed transpose ---------------------------------------
__global__ void transpose_qkv_kernel(const float* __restrict__ Wq, const float* __restrict__ Wk,
                                     const float* __restrict__ Wv, u16* __restrict__ out)
{
  __shared__ float tile[32][33];
  int l = blockIdx.z;
  int n0 = blockIdx.x * 32, k0 = blockIdx.y * 32;
  const float* W = (n0 < 512) ? Wq : (n0 < 1024 ? Wk : Wv);
  int nn0 = n0 & 511;
  const float* src = W + (size_t)l * D_ * D_;
  u16* dst = out + (size_t)l * 3 * D_ * D_;
  int tx = threadIdx.x, ty = threadIdx.y;
  #pragma unroll
  for (int i = 0; i < 4; ++i)
    tile[ty + i*8][tx] = src[(size_t)(k0 + ty + i*8) * D_ + nn0 + tx];
  __syncthreads();
  #pragma unroll
  for (int i = 0; i < 4; ++i)
    dst[(size_t)(n0 + ty + i*8) * D_ + k0 + tx] = f2bf(tile[tx][ty + i*8]);
}

// ---------------- bias pack: bqkv[l][1536] -----------------------------------
__global__ void pack_bias_kernel(const float* __restrict__ bq, const float* __restrict__ bk,
                                 const float* __restrict__ bv, float* __restrict__ out)
{
  int l = blockIdx.x, t = threadIdx.x;  // 512 threads
  out[l*1536 + t]        = bq[l*512 + t];
  out[l*1536 + 512  + t] = bk[l*512 + t];
  out[l*1536 + 1024 + t] = bv[l*512 + t];
}

// ---------------- LayerNorm: one wave per row, 4 rows/block, no barriers -----
// OUTMODE 0: write bf16. OUTMODE 1: write f32 (final output).
template <int OUTMODE>
__global__ __launch_bounds__(256) void ln_kernel(const float* __restrict__ x,
    const float* __restrict__ g, const float* __restrict__ b, void* __restrict__ outp)
{
  int lane = threadIdx.x & 63;
  int row  = (blockIdx.x << 2) + (threadIdx.x >> 6);
  const float* xr = x + (size_t)row * D_;
  int d = lane * 8;
  float4 a0 = *(const float4*)(xr + d);
  float4 a1 = *(const float4*)(xr + d + 4);
  float s  = a0.x+a0.y+a0.z+a0.w + a1.x+a1.y+a1.z+a1.w;
  float s2 = a0.x*a0.x+a0.y*a0.y+a0.z*a0.z+a0.w*a0.w
           + a1.x*a1.x+a1.y*a1.y+a1.z*a1.z+a1.w*a1.w;
  #pragma unroll
  for (int off = 32; off > 0; off >>= 1){ s += __shfl_xor(s, off); s2 += __shfl_xor(s2, off); }
  float m  = s * (1.0f / D_);
  float var = s2 * (1.0f / D_) - m*m;   // population var, matches jnp.var
  float rs = rsqrtf(var + 1e-5f);
  float4 g0 = *(const float4*)(g + d), g1 = *(const float4*)(g + d + 4);
  float4 b0 = *(const float4*)(b + d), b1 = *(const float4*)(b + d + 4);
  float o[8];
  o[0]=(a0.x-m)*rs*g0.x+b0.x; o[1]=(a0.y-m)*rs*g0.y+b0.y;
  o[2]=(a0.z-m)*rs*g0.z+b0.z; o[3]=(a0.w-m)*rs*g0.w+b0.w;
  o[4]=(a1.x-m)*rs*g1.x+b1.x; o[5]=(a1.y-m)*rs*g1.y+b1.y;
  o[6]=(a1.z-m)*rs*g1.z+b1.z; o[7]=(a1.w-m)*rs*g1.w+b1.w;
  if (OUTMODE == 1){
    float* outr = (float*)outp + (size_t)row * D_ + d;
    *(float4*)(outr)     = make_float4(o[0],o[1],o[2],o[3]);
    *(float4*)(outr + 4) = make_float4(o[4],o[5],o[6],o[7]);
  } else {
    u16* outr = (u16*)outp + (size_t)row * D_ + d;
    ushort4 w0, w1;
    w0.x=f2bf(o[0]); w0.y=f2bf(o[1]); w0.z=f2bf(o[2]); w0.w=f2bf(o[3]);
    w1.x=f2bf(o[4]); w1.y=f2bf(o[5]); w1.z=f2bf(o[6]); w1.w=f2bf(o[7]);
    *(ushort4*)(outr)     = w0;
    *(ushort4*)(outr + 4) = w1;
  }
}

// ---------------- MFMA GEMM, double-buffered pipeline ------------------------
// C[M][N] = A[M][K](bf16) @ Bt[N][K](bf16)^T  [+bias][relu][+resid]
// tile 128(M) x TN(N), BK=32, 256 thr = 4 waves (2x2).
// Pipeline: stage(next); s_waitcnt vmcnt(S) [only current buf's loads];
// s_barrier; compute; s_barrier. Next tile's loads stay in flight across
// the barrier (no vmcnt(0) drain).
template <int TN>
__global__ __launch_bounds__(256) void mgemm_kernel(
    const u16* __restrict__ A, const u16* __restrict__ Bt,
    const float* __restrict__ bias, const float* __restrict__ resid,
    void* __restrict__ C, int M, int N, int K,
    int relu, int bf16out, size_t wstride, size_t cstride)
{
  constexpr int NT = TN / 32;            // 16-col tiles per wave sub-tile
  constexpr int SB = TN / 64;            // B stage insts per thread
  constexpr int S  = 2 + SB;             // total stage insts per thread/iter
  Bt += (size_t)blockIdx.z * wstride;
  size_t coff = (size_t)blockIdx.z * cstride;

  __shared__ u16 As[2][128 * 32];
  __shared__ u16 Bs[2][TN * 32];

  int tid  = threadIdx.x;
  int wave = tid >> 6, lane = tid & 63;
  int wm = wave >> 1, wn = wave & 1;
  int fm = lane & 15, fq = lane >> 4;

  int m0 = blockIdx.y * 128, n0 = blockIdx.x * TN;

  f4_t acc[4][NT];
  #pragma unroll
  for (int i = 0; i < 4; ++i)
    #pragma unroll
    for (int j = 0; j < NT; ++j) acc[i][j] = (f4_t)0.0f;

  int srow = lane >> 2;                  // staging row-in-chunk
  int selem = (lane & 3) << 3;           // staging k-element offset

  auto stage = [&](int bufi, int k0){
    #pragma unroll
    for (int j = 0; j < 2; ++j){
      int c = wave * 2 + j;
      ld_lds16(A + (size_t)(m0 + c*16 + srow) * K + k0 + selem, &As[bufi][c * 512]);
    }
    #pragma unroll
    for (int j = 0; j < SB; ++j){
      int c = wave * SB + j;
      ld_lds16(Bt + (size_t)(n0 + c*16 + srow) * K + k0 + selem, &Bs[bufi][c * 512]);
    }
  };

  stage(0, 0);
  int buf = 0;
  for (int k0 = 0; k0 < K; k0 += 32){
    if (k0 + 32 < K){
      stage(buf ^ 1, k0 + 32);
      asm volatile("s_waitcnt vmcnt(%0)" :: "n"(S) : "memory");
    } else {
      asm volatile("s_waitcnt vmcnt(0)" ::: "memory");
    }
    asm volatile("s_barrier" ::: "memory");

    bf8_t af[4], bfr[NT];
    #pragma unroll
    for (int mi = 0; mi < 4; ++mi)
      af[mi] = *(const bf8_t*)&As[buf][(wm*64 + mi*16 + fm) * 32 + fq*8];
    #pragma unroll
    for (int nj = 0; nj < NT; ++nj)
      bfr[nj] = *(const bf8_t*)&Bs[buf][(wn*(TN/2) + nj*16 + fm) * 32 + fq*8];
    #pragma unroll
    for (int mi = 0; mi < 4; ++mi)
      #pragma unroll
      for (int nj = 0; nj < NT; ++nj)
        acc[mi][nj] = __builtin_amdgcn_mfma_f32_16x16x32_bf16(af[mi], bfr[nj], acc[mi][nj], 0, 0, 0);

    asm volatile("s_barrier" ::: "memory");
    buf ^= 1;
  }

  // epilogue: C/D layout col = lane&15, row = (lane>>4)*4 + reg
  int rbase = m0 + wm*64, cbase = n0 + wn*(TN/2);
  #pragma unroll
  for (int mi = 0; mi < 4; ++mi){
    #pragma unroll
    for (int nj = 0; nj < NT; ++nj){
      int col = cbase + nj*16 + fm;
      float bia = bias ? bias[col] : 0.0f;
      #pragma unroll
      for (int r = 0; r < 4; ++r){
        int row = rbase + mi*16 + fq*4 + r;
        size_t idx = coff + (size_t)row * N + col;
        float val = acc[mi][nj][r] + bia;
        if (relu)  val = fmaxf(val, 0.0f);
        if (resid) val += resid[idx];
        if (bf16out) ((u16*)C)[idx] = f2bf(val);
        else         ((float*)C)[idx] = val;
      }
    }
  }
}

// ---------------- Fused chunked attention (single-wave MFMA) ------------------
__global__ __launch_bounds__(64) void attn_kernel(
    const u16* __restrict__ qkv, const u16* __restrict__ p,
    const float* __restrict__ pbu, const float* __restrict__ pbv,
    u16* __restrict__ o)
{
  int ci = blockIdx.x, h = blockIdx.y, b = blockIdx.z;
  int t0 = ci * CS_;
  int cb = ci - LC_; if (cb < 0) cb = 0;
  int c0 = cb * CS_;
  int ncol = (ci + 1) * CS_ - c0;   // 16..80

  __shared__ u16 smem[15648];
  u16* qu = smem;                         // [16][64]
  u16* qv = smem + 1024;                  // [16][64]
  u16* kp = smem + 2048;                  // [80][64] K tile
  u16* pp = smem + 2048 + 5120;           // [80][64] P tile
  float* vf  = (float*)(smem + 2048);     // [80][64] f32 (aliases kp+pp)
  float* psf = (float*)(smem + 12288);    // [16][105] f32

  int lane = threadIdx.x;
  int fm = lane & 15, fq = lane >> 4;

  const u16* kbase = qkv + ((size_t)(b*T_ + c0)) * 1536 + 512 + h*DK_;
  const u16* pbase = p + (size_t)c0 * D_ + h*DK_;
  int srow8 = lane >> 3, scol = (lane & 7) << 3;
  #pragma unroll
  for (int c = 0; c < 10; ++c){
    ld_lds16(kbase + (size_t)(c*8 + srow8) * 1536 + scol, kp + c*512);
    ld_lds16(pbase + (size_t)(c*8 + srow8) * D_   + scol, pp + c*512);
  }
  const u16* qbase = qkv + ((size_t)(b*T_ + t0)) * 1536 + h*DK_;
  #pragma unroll
  for (int it = 0; it < 4; ++it){
    int i = it*256 + lane*4; int r = i >> 6; int d = i & 63;
    ushort4 w = *(const ushort4*)(qbase + (size_t)r * 1536 + d);
    float4 bu = *(const float4*)(pbu + h*DK_ + d);
    float4 bv = *(const float4*)(pbv + h*DK_ + d);
    ushort4 ou, ov;
    ou.x = f2bf(bf2f(w.x) + bu.x); ou.y = f2bf(bf2f(w.y) + bu.y);
    ou.z = f2bf(bf2f(w.z) + bu.z); ou.w = f2bf(bf2f(w.w) + bu.w);
    ov.x = f2bf(bf2f(w.x) + bv.x); ov.y = f2bf(bf2f(w.y) + bv.y);
    ov.z = f2bf(bf2f(w.z) + bv.z); ov.w = f2bf(bf2f(w.w) + bv.w);
    *(ushort4*)(qu + r*64 + d) = ou;
    *(ushort4*)(qv + r*64 + d) = ov;
  }
  __syncthreads();

  bf8_t au0 = *(const bf8_t*)(qu + fm*64 + fq*8);
  bf8_t au1 = *(const bf8_t*)(qu + fm*64 + 32 + fq*8);
  bf8_t av0 = *(const bf8_t*)(qv + fm*64 + fq*8);
  bf8_t av1 = *(const bf8_t*)(qv + fm*64 + 32 + fq*8);
  f4_t acc[5];
  #pragma unroll
  for (int nt = 0; nt < 5; ++nt) acc[nt] = (f4_t)0.0f;
  #pragma unroll
  for (int nt = 0; nt < 5; ++nt){
    const u16* kr = kp + (nt*16 + fm)*64;
    const u16* pr = pp + (nt*16 + fm)*64;
    bf8_t bk0 = *(const bf8_t*)(kr + fq*8);
    bf8_t bk1 = *(const bf8_t*)(kr + 32 + fq*8);
    bf8_t bp0 = *(const bf8_t*)(pr + fq*8);
    bf8_t bp1 = *(const bf8_t*)(pr + 32 + fq*8);
    f4_t a = acc[nt];
    a = __builtin_amdgcn_mfma_f32_16x16x32_bf16(au0, bk0, a, 0, 0, 0);
    a = __builtin_amdgcn_mfma_f32_16x16x32_bf16(au1, bk1, a, 0, 0, 0);
    a = __builtin_amdgcn_mfma_f32_16x16x32_bf16(av0, bp0, a, 0, 0, 0);
    a = __builtin_amdgcn_mfma_f32_16x16x32_bf16(av1, bp1, a, 0, 0, 0);
    acc[nt] = a;
  }

  const float scale = 0.125f;
  float mx[4], sm[4];
  float e[5][4];
  #pragma unroll
  for (int r = 0; r < 4; ++r) mx[r] = -3.0e38f;
  #pragma unroll
  for (int nt = 0; nt < 5; ++nt){
    bool valid = (nt*16 + fm) < ncol;
    #pragma unroll
    for (int r = 0; r < 4; ++r){
      float v = valid ? acc[nt][r] : -3.0e38f;
      mx[r] = fmaxf(mx[r], v);
    }
  }
  #pragma unroll
  for (int r = 0; r < 4; ++r){
    #pragma unroll
    for (int m = 1; m < 16; m <<= 1) mx[r] = fmaxf(mx[r], __shfl_xor(mx[r], m));
    sm[r] = 0.0f;
  }
  #pragma unroll
  for (int nt = 0; nt < 5; ++nt){
    bool valid = (nt*16 + fm) < ncol;
    #pragma unroll
    for (int r = 0; r < 4; ++r){
      float ev = valid ? __expf((acc[nt][r] - mx[r]) * scale) : 0.0f;
      e[nt][r] = ev; sm[r] += ev;
    }
  }
  #pragma unroll
  for (int r = 0; r < 4; ++r){
    #pragma unroll
    for (int m = 1; m < 16; m <<= 1) sm[r] += __shfl_xor(sm[r], m);
    sm[r] = 1.0f / sm[r];
  }
  #pragma unroll
  for (int nt = 0; nt < 5; ++nt)
    #pragma unroll
    for (int r = 0; r < 4; ++r)
      psf[(fq*4 + r)*105 + nt*16 + fm] = e[nt][r] * sm[r];
  __syncthreads();

  const u16* vbase = qkv + ((size_t)(b*T_ + c0)) * 1536 + 1024 + h*DK_;
  #pragma unroll
  for (int it = 0; it < 20; ++it){
    int i = it*256 + lane*4; int s = i >> 6; int d = i & 63;
    ushort4 w = *(const ushort4*)(vbase + (size_t)s * 1536 + d);
    float4 f; f.x = bf2f(w.x); f.y = bf2f(w.y); f.z = bf2f(w.z); f.w = bf2f(w.w);
    *(float4*)(vf + s*64 + d) = f;
  }
  __syncthreads();

  float oacc[16];
  #pragma unroll
  for (int ii = 0; ii < 16; ++ii) oacc[ii] = 0.0f;
  const float* psr = psf + fm*105;
  const float* vcol = vf + fq*16;
  for (int s = 0; s < 80; ++s){
    float pv = psr[s];
    const float* vr = vcol + s*64;
    float4 v0 = *(const float4*)(vr);
    float4 v1 = *(const float4*)(vr + 4);
    float4 v2 = *(const float4*)(vr + 8);
    float4 v3 = *(const float4*)(vr + 12);
    oacc[0]  += pv*v0.x; oacc[1]  += pv*v0.y; oacc[2]  += pv*v0.z; oacc[3]  += pv*v0.w;
    oacc[4]  += pv*v1.x; oacc[5]  += pv*v1.y; oacc[6]  += pv*v1.z; oacc[7]  += pv*v1.w;
    oacc[8]  += pv*v2.x; oacc[9]  += pv*v2.y; oacc[10] += pv*v2.z; oacc[11] += pv*v2.w;
    oacc[12] += pv*v3.x; oacc[13] += pv*v3.y; oacc[14] += pv*v3.z; oacc[15] += pv*v3.w;
  }
  u16* ob = o + ((size_t)(b*T_ + t0 + fm)) * D_ + h*DK_ + fq*16;
  #pragma unroll
  for (int q4 = 0; q4 < 4; ++q4){
    ushort4 w;
    w.x = f2bf(oacc[q4*4+0]); w.y = f2bf(oacc[q4*4+1]);
    w.z = f2bf(oacc[q4*4+2]); w.w = f2bf(oacc[q4*4+3]);
    *(ushort4*)(ob + q4*4) = w;
  }
}

// ---------------- launcher ---------------------------------------------------
extern "C" void kernel_launch(void* const* d_in, const int* in_sizes, int n_in,
                              void* d_out, int out_size, void* d_ws, size_t ws_size,
                              hipStream_t stream)
{
  int s0 = (n_in >= 24) ? 0 : -1;
  const float* xs   = (const float*)d_in[0];
  const float* pe   = (const float*)d_in[1];
  const float* Wq   = (const float*)d_in[3  + s0];
  const float* bq   = (const float*)d_in[4  + s0];
  const float* Wk   = (const float*)d_in[5  + s0];
  const float* bk   = (const float*)d_in[6  + s0];
  const float* Wv   = (const float*)d_in[7  + s0];
  const float* bv   = (const float*)d_in[8  + s0];
  const float* Wo   = (const float*)d_in[9  + s0];
  const float* bo   = (const float*)d_in[10 + s0];
  const float* Wp   = (const float*)d_in[11 + s0];
  const float* pbu  = (const float*)d_in[12 + s0];
  const float* pbv  = (const float*)d_in[13 + s0];
  const float* ln1s = (const float*)d_in[14 + s0];
  const float* ln1b = (const float*)d_in[15 + s0];
  const float* ln2s = (const float*)d_in[16 + s0];
  const float* ln2b = (const float*)d_in[17 + s0];
  const float* W1   = (const float*)d_in[18 + s0];
  const float* b1   = (const float*)d_in[19 + s0];
  const float* W2   = (const float*)d_in[20 + s0];
  const float* b2   = (const float*)d_in[21 + s0];
  const float* lnfs = (const float*)d_in[22 + s0];
  const float* lnfb = (const float*)d_in[23 + s0];

  float* ws = (float*)d_ws;
  size_t cur = 0;
  float* x      = ws + cur;            cur += (size_t)MT_*D_;
  u16*   region = (u16*)(ws + cur);    cur += (size_t)MT_*FF_/2;
  u16*   qkv_bf = region;
  u16*   ff_bf  = region;
  u16*   h_bf   = (u16*)(ws + cur);    cur += (size_t)MT_*D_/2;
  u16*   ob_bf  = (u16*)(ws + cur);    cur += (size_t)MT_*D_/2;
  u16*   pe_bf  = (u16*)(ws + cur);    cur += (size_t)T_*D_/2;
  u16*   pbuf   = (u16*)(ws + cur);    cur += (size_t)L_*T_*D_/2;
  u16*   qkvt   = (u16*)(ws + cur);    cur += (size_t)L_*3*D_*D_/2;
  u16*   wot    = (u16*)(ws + cur);    cur += (size_t)L_*D_*D_/2;
  u16*   w1t    = (u16*)(ws + cur);    cur += (size_t)L_*D_*FF_/2;
  u16*   w2t    = (u16*)(ws + cur);    cur += (size_t)L_*FF_*D_/2;
  u16*   wpt    = (u16*)(ws + cur);    cur += (size_t)L_*D_*D_/2;
  float* bqkv   = ws + cur;            cur += (size_t)L_*3*D_;

  dim3 tb(32, 8);
  transpose_qkv_kernel<<<dim3(48, 16, L_), tb, 0, stream>>>(Wq, Wk, Wv, qkvt);
  transpose_kernel<<<dim3(16, 16, L_), tb, 0, stream>>>(Wo, wot, D_, D_);
  transpose_kernel<<<dim3(64, 16, L_), tb, 0, stream>>>(W1, w1t, D_, FF_);
  transpose_kernel<<<dim3(16, 64, L_), tb, 0, stream>>>(W2, w2t, FF_, D_);
  transpose_kernel<<<dim3(16, 16, L_), tb, 0, stream>>>(Wp, wpt, D_, D_);
  pack_bias_kernel<<<dim3(L_), dim3(512), 0, stream>>>(bq, bk, bv, bqkv);
  init_kernel<<<dim3(512), dim3(256), 0, stream>>>(xs, pe, x, pe_bf);

  dim3 blk(256);
  // P[l] = pe @ Wp[l]: M=512,N=512,K=512, z=6, bf16 out
  mgemm_kernel<64><<<dim3(8, 4, L_), blk, 0, stream>>>(
      pe_bf, wpt, nullptr, nullptr, pbuf, T_, D_, D_, 0, 1,
      (size_t)D_*D_, (size_t)T_*D_);

  for (int l = 0; l < L_; ++l){
    ln_kernel<0><<<dim3(MT_/4), blk, 0, stream>>>(x, ln1s + l*D_, ln1b + l*D_, h_bf);
    mgemm_kernel<128><<<dim3(12, 32, 1), blk, 0, stream>>>(
        h_bf, qkvt + (size_t)l*3*D_*D_, bqkv + l*3*D_, nullptr, qkv_bf,
        MT_, 3*D_, D_, 0, 1, 0, 0);
    attn_kernel<<<dim3(T_/CS_, H_, B_), dim3(64), 0, stream>>>(
        qkv_bf, pbuf + (size_t)l*T_*D_, pbu + l*H_*DK_, pbv + l*H_*DK_, ob_bf);
    mgemm_kernel<64><<<dim3(8, 32, 1), blk, 0, stream>>>(
        ob_bf, wot + (size_t)l*D_*D_, bo + l*D_, x, x, MT_, D_, D_, 0, 0, 0, 0);
    ln_kernel<0><<<dim3(MT_/4), blk, 0, stream>>>(x, ln2s + l*D_, ln2b + l*D_, h_bf);
    mgemm_kernel<128><<<dim3(16, 32, 1), blk, 0, stream>>>(
        h_bf, w1t + (size_t)l*D_*FF_, b1 + l*FF_, nullptr, ff_bf,
        MT_, FF_, D_, 1, 1, 0, 0);
    mgemm_kernel<64><<<dim3(8, 32, 1), blk, 0, stream>>>(
        ff_bf, w2t + (size_t)l*FF_*D_, b2 + l*D_, x, x, MT_, D_, FF_, 0, 0, 0, 0);
  }
  ln_kernel<1><<<dim3(MT_/4), blk, 0, stream>>>(x, lnfs, lnfb, d_out);
}

// Round 8
// 971.146 us; speedup vs baseline: 5.4929x; 1.0077x over previous
//
#include <hip/hip_runtime.h>

// Problem constants (B,T,D,H,FF,L,CS,LC) = (8,512,512,8,2048,6,16,4)
#define B_ 8
#define T_ 512
#define D_ 512
#define H_ 8
#define FF_ 2048
#define L_ 6
#define CS_ 16
#define LC_ 4
#define DK_ 64
#define MT_ (B_*T_)   // 4096 rows

typedef unsigned short u16;  // raw bf16
typedef __attribute__((ext_vector_type(8))) short bf8_t;   // 8 x bf16 (4 VGPR)
typedef __attribute__((ext_vector_type(4))) float f4_t;    // 4 x f32 acc

__device__ __forceinline__ float bf2f(u16 u){
  union { unsigned int i; float f; } c; c.i = ((unsigned int)u) << 16; return c.f;
}
__device__ __forceinline__ u16 f2bf(float f){
  union { float f; unsigned int i; } c; c.f = f;
  unsigned int x = c.i;
  return (u16)((x + 0x7FFFu + ((x >> 16) & 1u)) >> 16);  // RNE
}
__device__ __forceinline__ void ld_lds16(const u16* gp, u16* lp){
  __builtin_amdgcn_global_load_lds((const __attribute__((address_space(1))) void*)gp,
                                   (__attribute__((address_space(3))) void*)lp, 16, 0, 0);
}

// ---------------- init: x = xs*sqrt(D) (f32), pe_bf = bf16(pos_emb) ----------
__global__ void init_kernel(const float* __restrict__ xs, const float* __restrict__ pe,
                            float* __restrict__ x, u16* __restrict__ pe_bf)
{
  int stride = gridDim.x * blockDim.x;
  int i0 = blockIdx.x * blockDim.x + threadIdx.x;
  const float s = 22.62741699796952f;  // sqrt(512)
  for (int i = i0; i < B_*T_*D_; i += stride) x[i] = xs[i] * s;
  for (int i = i0; i < T_*D_;    i += stride) pe_bf[i] = f2bf(pe[i]);
}

// ---------------- generic transpose+convert: in f32 [K][N] -> out bf16 [N][K]
__global__ void transpose_kernel(const float* __restrict__ in, u16* __restrict__ out,
                                 int K, int N)
{
  __shared__ float tile[32][33];
  int l = blockIdx.z;
  const float* src = in + (size_t)l * K * N;
  u16* dst = out + (size_t)l * N * K;
  int n0 = blockIdx.x * 32, k0 = blockIdx.y * 32;
  int tx = threadIdx.x, ty = threadIdx.y;
  #pragma unroll
  for (int i = 0; i < 4; ++i)
    tile[ty + i*8][tx] = src[(size_t)(k0 + ty + i*8) * N + n0 + tx];
  __syncthreads();
  #pragma unroll
  for (int i = 0; i < 4; ++i)
    dst[(size_t)(n0 + ty + i*8) * K + k0 + tx] = f2bf(tile[tx][ty + i*8]);
}

// ---------------- QKV packed transpose ---------------------------------------
__global__ void transpose_qkv_kernel(const float* __restrict__ Wq, const float* __restrict__ Wk,
                                     const float* __restrict__ Wv, u16* __restrict__ out)
{
  __shared__ float tile[32][33];
  int l = blockIdx.z;
  int n0 = blockIdx.x * 32, k0 = blockIdx.y * 32;
  const float* W = (n0 < 512) ? Wq : (n0 < 1024 ? Wk : Wv);
  int nn0 = n0 & 511;
  const float* src = W + (size_t)l * D_ * D_;
  u16* dst = out + (size_t)l * 3 * D_ * D_;
  int tx = threadIdx.x, ty = threadIdx.y;
  #pragma unroll
  for (int i = 0; i < 4; ++i)
    tile[ty + i*8][tx] = src[(size_t)(k0 + ty + i*8) * D_ + nn0 + tx];
  __syncthreads();
  #pragma unroll
  for (int i = 0; i < 4; ++i)
    dst[(size_t)(n0 + ty + i*8) * D_ + k0 + tx] = f2bf(tile[tx][ty + i*8]);
}

// ---------------- bias pack: bqkv[l][1536] -----------------------------------
__global__ void pack_bias_kernel(const float* __restrict__ bq, const float* __restrict__ bk,
                                 const float* __restrict__ bv, float* __restrict__ out)
{
  int l = blockIdx.x, t = threadIdx.x;  // 512 threads
  out[l*1536 + t]        = bq[l*512 + t];
  out[l*1536 + 512  + t] = bk[l*512 + t];
  out[l*1536 + 1024 + t] = bv[l*512 + t];
}

// ---------------- LayerNorm: one wave per row, 4 rows/block ------------------
template <int OUTMODE>
__global__ __launch_bounds__(256) void ln_kernel(const float* __restrict__ x,
    const float* __restrict__ g, const float* __restrict__ b, void* __restrict__ outp)
{
  int lane = threadIdx.x & 63;
  int row  = (blockIdx.x << 2) + (threadIdx.x >> 6);
  const float* xr = x + (size_t)row * D_;
  int d = lane * 8;
  float4 a0 = *(const float4*)(xr + d);
  float4 a1 = *(const float4*)(xr + d + 4);
  float s  = a0.x+a0.y+a0.z+a0.w + a1.x+a1.y+a1.z+a1.w;
  float s2 = a0.x*a0.x+a0.y*a0.y+a0.z*a0.z+a0.w*a0.w
           + a1.x*a1.x+a1.y*a1.y+a1.z*a1.z+a1.w*a1.w;
  #pragma unroll
  for (int off = 32; off > 0; off >>= 1){ s += __shfl_xor(s, off); s2 += __shfl_xor(s2, off); }
  float m  = s * (1.0f / D_);
  float var = s2 * (1.0f / D_) - m*m;
  float rs = rsqrtf(var + 1e-5f);
  float4 g0 = *(const float4*)(g + d), g1 = *(const float4*)(g + d + 4);
  float4 b0 = *(const float4*)(b + d), b1 = *(const float4*)(b + d + 4);
  float o[8];
  o[0]=(a0.x-m)*rs*g0.x+b0.x; o[1]=(a0.y-m)*rs*g0.y+b0.y;
  o[2]=(a0.z-m)*rs*g0.z+b0.z; o[3]=(a0.w-m)*rs*g0.w+b0.w;
  o[4]=(a1.x-m)*rs*g1.x+b1.x; o[5]=(a1.y-m)*rs*g1.y+b1.y;
  o[6]=(a1.z-m)*rs*g1.z+b1.z; o[7]=(a1.w-m)*rs*g1.w+b1.w;
  if (OUTMODE == 1){
    float* outr = (float*)outp + (size_t)row * D_ + d;
    *(float4*)(outr)     = make_float4(o[0],o[1],o[2],o[3]);
    *(float4*)(outr + 4) = make_float4(o[4],o[5],o[6],o[7]);
  } else {
    u16* outr = (u16*)outp + (size_t)row * D_ + d;
    ushort4 w0, w1;
    w0.x=f2bf(o[0]); w0.y=f2bf(o[1]); w0.z=f2bf(o[2]); w0.w=f2bf(o[3]);
    w1.x=f2bf(o[4]); w1.y=f2bf(o[5]); w1.z=f2bf(o[6]); w1.w=f2bf(o[7]);
    *(ushort4*)(outr)     = w0;
    *(ushort4*)(outr + 4) = w1;
  }
}

// ---------------- MFMA GEMM: 3-deep pipeline, optional split-K+atomic --------
// C[M][N] = A[M][K](bf16) @ Bt[N][K](bf16)^T
// tile 128(M) x 64(N), BK=32, 256 thr = 4 waves (2x2), wave tile 64x32.
// kchunk==0: z indexes weight matrices (wstride/cstride); normal epilogue
//            [+bias][relu][+resid], out f32/bf16.
// kchunk>0:  z indexes K-chunks of size kchunk; epilogue atomicAdd f32 into C
//            (C must hold the residual); bias added only by z==0.
__global__ __launch_bounds__(256) void mgemm_kernel(
    const u16* __restrict__ A, const u16* __restrict__ Bt,
    const float* __restrict__ bias, const float* __restrict__ resid,
    void* __restrict__ C, int M, int N, int K,
    int relu, int bf16out, size_t wstride, size_t cstride, int kchunk)
{
  constexpr int TN = 64, NT = 2, S = 3;  // 2 A-insts + 1 B-inst per thread/stage
  size_t coff = 0;
  int kbeg = 0, kend = K;
  if (kchunk > 0){
    kbeg = blockIdx.z * kchunk; kend = kbeg + kchunk;
  } else {
    Bt += (size_t)blockIdx.z * wstride;
    coff = (size_t)blockIdx.z * cstride;
  }

  __shared__ u16 As[3][128 * 32];
  __shared__ u16 Bs[3][TN * 32];

  int tid  = threadIdx.x;
  int wave = tid >> 6, lane = tid & 63;
  int wm = wave >> 1, wn = wave & 1;
  int fm = lane & 15, fq = lane >> 4;

  int m0 = blockIdx.y * 128, n0 = blockIdx.x * TN;

  f4_t acc[4][NT];
  #pragma unroll
  for (int i = 0; i < 4; ++i)
    #pragma unroll
    for (int j = 0; j < NT; ++j) acc[i][j] = (f4_t)0.0f;

  int srow = lane >> 2;
  int selem = (lane & 3) << 3;

  auto stage = [&](int bufi, int k0){
    #pragma unroll
    for (int j = 0; j < 2; ++j){
      int c = wave * 2 + j;
      ld_lds16(A + (size_t)(m0 + c*16 + srow) * K + k0 + selem, &As[bufi][c * 512]);
    }
    ld_lds16(Bt + (size_t)(n0 + wave*16 + srow) * K + k0 + selem, &Bs[bufi][wave * 512]);
  };

  stage(0, kbeg);
  if (kbeg + 32 < kend) stage(1, kbeg + 32);
  int buf = 0;
  for (int k0 = kbeg; k0 < kend; k0 += 32){
    if (k0 + 64 < kend){
      stage((buf + 2) % 3, k0 + 64);
      asm volatile("s_waitcnt vmcnt(%0)" :: "n"(2*S) : "memory");
    } else if (k0 + 32 < kend){
      asm volatile("s_waitcnt vmcnt(%0)" :: "n"(S) : "memory");
    } else {
      asm volatile("s_waitcnt vmcnt(0)" ::: "memory");
    }
    asm volatile("s_barrier" ::: "memory");

    bf8_t af[4], bfr[NT];
    #pragma unroll
    for (int mi = 0; mi < 4; ++mi)
      af[mi] = *(const bf8_t*)&As[buf][(wm*64 + mi*16 + fm) * 32 + fq*8];
    #pragma unroll
    for (int nj = 0; nj < NT; ++nj)
      bfr[nj] = *(const bf8_t*)&Bs[buf][(wn*32 + nj*16 + fm) * 32 + fq*8];
    #pragma unroll
    for (int mi = 0; mi < 4; ++mi)
      #pragma unroll
      for (int nj = 0; nj < NT; ++nj)
        acc[mi][nj] = __builtin_amdgcn_mfma_f32_16x16x32_bf16(af[mi], bfr[nj], acc[mi][nj], 0, 0, 0);

    asm volatile("s_barrier" ::: "memory");
    buf = (buf + 1) % 3;
  }

  // epilogue: C/D layout col = lane&15, row = (lane>>4)*4 + reg
  int rbase = m0 + wm*64, cbase = n0 + wn*32;
  if (kchunk > 0){
    int addb = (blockIdx.z == 0) && bias;
    #pragma unroll
    for (int mi = 0; mi < 4; ++mi){
      #pragma unroll
      for (int nj = 0; nj < NT; ++nj){
        int col = cbase + nj*16 + fm;
        float bia = addb ? bias[col] : 0.0f;
        #pragma unroll
        for (int r = 0; r < 4; ++r){
          int row = rbase + mi*16 + fq*4 + r;
          atomicAdd((float*)C + (size_t)row * N + col, acc[mi][nj][r] + bia);
        }
      }
    }
  } else {
    #pragma unroll
    for (int mi = 0; mi < 4; ++mi){
      #pragma unroll
      for (int nj = 0; nj < NT; ++nj){
        int col = cbase + nj*16 + fm;
        float bia = bias ? bias[col] : 0.0f;
        #pragma unroll
        for (int r = 0; r < 4; ++r){
          int row = rbase + mi*16 + fq*4 + r;
          size_t idx = coff + (size_t)row * N + col;
          float val = acc[mi][nj][r] + bia;
          if (relu)  val = fmaxf(val, 0.0f);
          if (resid) val += resid[idx];
          if (bf16out) ((u16*)C)[idx] = f2bf(val);
          else         ((float*)C)[idx] = val;
        }
      }
    }
  }
}

// ---------------- Fused chunked attention (single-wave MFMA) ------------------
__global__ __launch_bounds__(64) void attn_kernel(
    const u16* __restrict__ qkv, const u16* __restrict__ p,
    const float* __restrict__ pbu, const float* __restrict__ pbv,
    u16* __restrict__ o)
{
  int ci = blockIdx.x, h = blockIdx.y, b = blockIdx.z;
  int t0 = ci * CS_;
  int cb = ci - LC_; if (cb < 0) cb = 0;
  int c0 = cb * CS_;
  int ncol = (ci + 1) * CS_ - c0;   // 16..80

  __shared__ u16 smem[15648];
  u16* qu = smem;                         // [16][64]
  u16* qv = smem + 1024;                  // [16][64]
  u16* kp = smem + 2048;                  // [80][64] K tile
  u16* pp = smem + 2048 + 5120;           // [80][64] P tile
  float* vf  = (float*)(smem + 2048);     // [80][64] f32 (aliases kp+pp)
  float* psf = (float*)(smem + 12288);    // [16][105] f32

  int lane = threadIdx.x;
  int fm = lane & 15, fq = lane >> 4;

  const u16* kbase = qkv + ((size_t)(b*T_ + c0)) * 1536 + 512 + h*DK_;
  const u16* pbase = p + (size_t)c0 * D_ + h*DK_;
  int srow8 = lane >> 3, scol = (lane & 7) << 3;
  #pragma unroll
  for (int c = 0; c < 10; ++c){
    ld_lds16(kbase + (size_t)(c*8 + srow8) * 1536 + scol, kp + c*512);
    ld_lds16(pbase + (size_t)(c*8 + srow8) * D_   + scol, pp + c*512);
  }
  const u16* qbase = qkv + ((size_t)(b*T_ + t0)) * 1536 + h*DK_;
  #pragma unroll
  for (int it = 0; it < 4; ++it){
    int i = it*256 + lane*4; int r = i >> 6; int d = i & 63;
    ushort4 w = *(const ushort4*)(qbase + (size_t)r * 1536 + d);
    float4 bu = *(const float4*)(pbu + h*DK_ + d);
    float4 bv = *(const float4*)(pbv + h*DK_ + d);
    ushort4 ou, ov;
    ou.x = f2bf(bf2f(w.x) + bu.x); ou.y = f2bf(bf2f(w.y) + bu.y);
    ou.z = f2bf(bf2f(w.z) + bu.z); ou.w = f2bf(bf2f(w.w) + bu.w);
    ov.x = f2bf(bf2f(w.x) + bv.x); ov.y = f2bf(bf2f(w.y) + bv.y);
    ov.z = f2bf(bf2f(w.z) + bv.z); ov.w = f2bf(bf2f(w.w) + bv.w);
    *(ushort4*)(qu + r*64 + d) = ou;
    *(ushort4*)(qv + r*64 + d) = ov;
  }
  __syncthreads();

  bf8_t au0 = *(const bf8_t*)(qu + fm*64 + fq*8);
  bf8_t au1 = *(const bf8_t*)(qu + fm*64 + 32 + fq*8);
  bf8_t av0 = *(const bf8_t*)(qv + fm*64 + fq*8);
  bf8_t av1 = *(const bf8_t*)(qv + fm*64 + 32 + fq*8);
  f4_t acc[5];
  #pragma unroll
  for (int nt = 0; nt < 5; ++nt) acc[nt] = (f4_t)0.0f;
  #pragma unroll
  for (int nt = 0; nt < 5; ++nt){
    const u16* kr = kp + (nt*16 + fm)*64;
    const u16* pr = pp + (nt*16 + fm)*64;
    bf8_t bk0 = *(const bf8_t*)(kr + fq*8);
    bf8_t bk1 = *(const bf8_t*)(kr + 32 + fq*8);
    bf8_t bp0 = *(const bf8_t*)(pr + fq*8);
    bf8_t bp1 = *(const bf8_t*)(pr + 32 + fq*8);
    f4_t a = acc[nt];
    a = __builtin_amdgcn_mfma_f32_16x16x32_bf16(au0, bk0, a, 0, 0, 0);
    a = __builtin_amdgcn_mfma_f32_16x16x32_bf16(au1, bk1, a, 0, 0, 0);
    a = __builtin_amdgcn_mfma_f32_16x16x32_bf16(av0, bp0, a, 0, 0, 0);
    a = __builtin_amdgcn_mfma_f32_16x16x32_bf16(av1, bp1, a, 0, 0, 0);
    acc[nt] = a;
  }

  const float scale = 0.125f;
  float mx[4], sm[4];
  float e[5][4];
  #pragma unroll
  for (int r = 0; r < 4; ++r) mx[r] = -3.0e38f;
  #pragma unroll
  for (int nt = 0; nt < 5; ++nt){
    bool valid = (nt*16 + fm) < ncol;
    #pragma unroll
    for (int r = 0; r < 4; ++r){
      float v = valid ? acc[nt][r] : -3.0e38f;
      mx[r] = fmaxf(mx[r], v);
    }
  }
  #pragma unroll
  for (int r = 0; r < 4; ++r){
    #pragma unroll
    for (int m = 1; m < 16; m <<= 1) mx[r] = fmaxf(mx[r], __shfl_xor(mx[r], m));
    sm[r] = 0.0f;
  }
  #pragma unroll
  for (int nt = 0; nt < 5; ++nt){
    bool valid = (nt*16 + fm) < ncol;
    #pragma unroll
    for (int r = 0; r < 4; ++r){
      float ev = valid ? __expf((acc[nt][r] - mx[r]) * scale) : 0.0f;
      e[nt][r] = ev; sm[r] += ev;
    }
  }
  #pragma unroll
  for (int r = 0; r < 4; ++r){
    #pragma unroll
    for (int m = 1; m < 16; m <<= 1) sm[r] += __shfl_xor(sm[r], m);
    sm[r] = 1.0f / sm[r];
  }
  #pragma unroll
  for (int nt = 0; nt < 5; ++nt)
    #pragma unroll
    for (int r = 0; r < 4; ++r)
      psf[(fq*4 + r)*105 + nt*16 + fm] = e[nt][r] * sm[r];
  __syncthreads();

  const u16* vbase = qkv + ((size_t)(b*T_ + c0)) * 1536 + 1024 + h*DK_;
  #pragma unroll
  for (int it = 0; it < 20; ++it){
    int i = it*256 + lane*4; int s = i >> 6; int d = i & 63;
    ushort4 w = *(const ushort4*)(vbase + (size_t)s * 1536 + d);
    float4 f; f.x = bf2f(w.x); f.y = bf2f(w.y); f.z = bf2f(w.z); f.w = bf2f(w.w);
    *(float4*)(vf + s*64 + d) = f;
  }
  __syncthreads();

  float oacc[16];
  #pragma unroll
  for (int ii = 0; ii < 16; ++ii) oacc[ii] = 0.0f;
  const float* psr = psf + fm*105;
  const float* vcol = vf + fq*16;
  for (int s = 0; s < 80; ++s){
    float pv = psr[s];
    const float* vr = vcol + s*64;
    float4 v0 = *(const float4*)(vr);
    float4 v1 = *(const float4*)(vr + 4);
    float4 v2 = *(const float4*)(vr + 8);
    float4 v3 = *(const float4*)(vr + 12);
    oacc[0]  += pv*v0.x; oacc[1]  += pv*v0.y; oacc[2]  += pv*v0.z; oacc[3]  += pv*v0.w;
    oacc[4]  += pv*v1.x; oacc[5]  += pv*v1.y; oacc[6]  += pv*v1.z; oacc[7]  += pv*v1.w;
    oacc[8]  += pv*v2.x; oacc[9]  += pv*v2.y; oacc[10] += pv*v2.z; oacc[11] += pv*v2.w;
    oacc[12] += pv*v3.x; oacc[13] += pv*v3.y; oacc[14] += pv*v3.z; oacc[15] += pv*v3.w;
  }
  u16* ob = o + ((size_t)(b*T_ + t0 + fm)) * D_ + h*DK_ + fq*16;
  #pragma unroll
  for (int q4 = 0; q4 < 4; ++q4){
    ushort4 w;
    w.x = f2bf(oacc[q4*4+0]); w.y = f2bf(oacc[q4*4+1]);
    w.z = f2bf(oacc[q4*4+2]); w.w = f2bf(oacc[q4*4+3]);
    *(ushort4*)(ob + q4*4) = w;
  }
}

// ---------------- launcher ---------------------------------------------------
extern "C" void kernel_launch(void* const* d_in, const int* in_sizes, int n_in,
                              void* d_out, int out_size, void* d_ws, size_t ws_size,
                              hipStream_t stream)
{
  int s0 = (n_in >= 24) ? 0 : -1;
  const float* xs   = (const float*)d_in[0];
  const float* pe   = (const float*)d_in[1];
  const float* Wq   = (const float*)d_in[3  + s0];
  const float* bq   = (const float*)d_in[4  + s0];
  const float* Wk   = (const float*)d_in[5  + s0];
  const float* bk   = (const float*)d_in[6  + s0];
  const float* Wv   = (const float*)d_in[7  + s0];
  const float* bv   = (const float*)d_in[8  + s0];
  const float* Wo   = (const float*)d_in[9  + s0];
  const float* bo   = (const float*)d_in[10 + s0];
  const float* Wp   = (const float*)d_in[11 + s0];
  const float* pbu  = (const float*)d_in[12 + s0];
  const float* pbv  = (const float*)d_in[13 + s0];
  const float* ln1s = (const float*)d_in[14 + s0];
  const float* ln1b = (const float*)d_in[15 + s0];
  const float* ln2s = (const float*)d_in[16 + s0];
  const float* ln2b = (const float*)d_in[17 + s0];
  const float* W1   = (const float*)d_in[18 + s0];
  const float* b1   = (const float*)d_in[19 + s0];
  const float* W2   = (const float*)d_in[20 + s0];
  const float* b2   = (const float*)d_in[21 + s0];
  const float* lnfs = (const float*)d_in[22 + s0];
  const float* lnfb = (const float*)d_in[23 + s0];

  float* ws = (float*)d_ws;
  size_t cur = 0;
  float* x      = ws + cur;            cur += (size_t)MT_*D_;
  u16*   region = (u16*)(ws + cur);    cur += (size_t)MT_*FF_/2;
  u16*   qkv_bf = region;
  u16*   ff_bf  = region;
  u16*   h_bf   = (u16*)(ws + cur);    cur += (size_t)MT_*D_/2;
  u16*   ob_bf  = (u16*)(ws + cur);    cur += (size_t)MT_*D_/2;
  u16*   pe_bf  = (u16*)(ws + cur);    cur += (size_t)T_*D_/2;
  u16*   pbuf   = (u16*)(ws + cur);    cur += (size_t)L_*T_*D_/2;
  u16*   qkvt   = (u16*)(ws + cur);    cur += (size_t)L_*3*D_*D_/2;
  u16*   wot    = (u16*)(ws + cur);    cur += (size_t)L_*D_*D_/2;
  u16*   w1t    = (u16*)(ws + cur);    cur += (size_t)L_*D_*FF_/2;
  u16*   w2t    = (u16*)(ws + cur);    cur += (size_t)L_*FF_*D_/2;
  u16*   wpt    = (u16*)(ws + cur);    cur += (size_t)L_*D_*D_/2;
  float* bqkv   = ws + cur;            cur += (size_t)L_*3*D_;

  dim3 tb(32, 8);
  transpose_qkv_kernel<<<dim3(48, 16, L_), tb, 0, stream>>>(Wq, Wk, Wv, qkvt);
  transpose_kernel<<<dim3(16, 16, L_), tb, 0, stream>>>(Wo, wot, D_, D_);
  transpose_kernel<<<dim3(64, 16, L_), tb, 0, stream>>>(W1, w1t, D_, FF_);
  transpose_kernel<<<dim3(16, 64, L_), tb, 0, stream>>>(W2, w2t, FF_, D_);
  transpose_kernel<<<dim3(16, 16, L_), tb, 0, stream>>>(Wp, wpt, D_, D_);
  pack_bias_kernel<<<dim3(L_), dim3(512), 0, stream>>>(bq, bk, bv, bqkv);
  init_kernel<<<dim3(512), dim3(256), 0, stream>>>(xs, pe, x, pe_bf);

  dim3 blk(256);
  // P[l] = pe @ Wp[l]: M=512,N=512,K=512, z indexes layers, bf16 out
  mgemm_kernel<<<dim3(8, 4, L_), blk, 0, stream>>>(
      pe_bf, wpt, nullptr, nullptr, pbuf, T_, D_, D_, 0, 1,
      (size_t)D_*D_, (size_t)T_*D_, 0);

  for (int l = 0; l < L_; ++l){
    ln_kernel<0><<<dim3(MT_/4), blk, 0, stream>>>(x, ln1s + l*D_, ln1b + l*D_, h_bf);
    // QKV: M=4096, N=1536, K=512, grid 24x32 = 768 blocks, bf16 out
    mgemm_kernel<<<dim3(24, 32, 1), blk, 0, stream>>>(
        h_bf, qkvt + (size_t)l*3*D_*D_, bqkv + l*3*D_, nullptr, qkv_bf,
        MT_, 3*D_, D_, 0, 1, 0, 0, 0);
    attn_kernel<<<dim3(T_/CS_, H_, B_), dim3(64), 0, stream>>>(
        qkv_bf, pbuf + (size_t)l*T_*D_, pbu + l*H_*DK_, pbv + l*H_*DK_, ob_bf);
    // O-proj: split-K=2 (kchunk=256), atomic into x (x holds residual)
    mgemm_kernel<<<dim3(8, 32, 2), blk, 0, stream>>>(
        ob_bf, wot + (size_t)l*D_*D_, bo + l*D_, nullptr, x,
        MT_, D_, D_, 0, 0, 0, 0, 256);
    ln_kernel<0><<<dim3(MT_/4), blk, 0, stream>>>(x, ln2s + l*D_, ln2b + l*D_, h_bf);
    // FF1: M=4096, N=2048, K=512, grid 32x32 = 1024 blocks, relu, bf16 out
    mgemm_kernel<<<dim3(32, 32, 1), blk, 0, stream>>>(
        h_bf, w1t + (size_t)l*D_*FF_, b1 + l*FF_, nullptr, ff_bf,
        MT_, FF_, D_, 1, 1, 0, 0, 0);
    // FF2: split-K=4 (kchunk=512), atomic into x
    mgemm_kernel<<<dim3(8, 32, 4), blk, 0, stream>>>(
        ff_bf, w2t + (size_t)l*FF_*D_, b2 + l*D_, nullptr, x,
        MT_, D_, FF_, 0, 0, 0, 0, 512);
  }
  ln_kernel<1><<<dim3(MT_/4), blk, 0, stream>>>(x, lnfs, lnfb, d_out);
}